// Round 13
// baseline (216.359 us; speedup 1.0000x reference)
//
#include <hip/hip_runtime.h>

#define B_  4
#define L_  1024
#define D_  512
#define H_  8
#define DK_ 64
#define BL_ (B_*L_)

typedef unsigned short us16;   // raw bf16 bits
typedef __attribute__((ext_vector_type(8))) short bf16x8;
typedef __attribute__((ext_vector_type(4))) float f32x4;

__device__ __forceinline__ float us2f(us16 u) {
  union { unsigned int i; float f; } x;
  x.i = ((unsigned int)u) << 16;
  return x.f;
}
__device__ __forceinline__ us16 f2us(float f) {
  union { float f; unsigned int i; } x;
  x.f = f;
  unsigned int r = x.i + 0x7FFFu + ((x.i >> 16) & 1u);  // RNE
  return (us16)(r >> 16);
}
__device__ __forceinline__ us16 cvt_us(float f) { return f2us(f); }
__device__ __forceinline__ us16 cvt_us(us16 u) { return u; }
// hardware base-2 exp (v_exp_f32); args here are bounded (|x| < ~8)
__device__ __forceinline__ float fexp2(float x) {
  return __builtin_amdgcn_exp2f(x);
}

#define MFMA(a, b, c) __builtin_amdgcn_mfma_f32_16x16x32_bf16(a, b, c, 0, 0, 0)

typedef const __attribute__((address_space(1))) unsigned int* gas_u32;
typedef __attribute__((address_space(3))) unsigned int* las_u32;

// ---- async tile staging helpers (attn8-validated pattern) ------------------
// stg8: DMA 8 rows x 128B from rowbase (ld=512 us16) into 1KB linear LDS.
// lane l: source row l>>3, source 16B-block (l&7)^(l>>3)  [XOR involution];
// dest = dst + l*16B (linear, HW-enforced).
__device__ __forceinline__ void stg8(const us16* rowbase, us16* dst, int lane) {
  const us16* src = rowbase + (size_t)(lane >> 3) * 512 +
                    (((lane & 7) ^ (lane >> 3)) * 8);
  __builtin_amdgcn_global_load_lds((gas_u32)src, (las_u32)dst, 16, 0, 0);
}
// rdz: read global 16B-block `blk` of row `row` from a swizzled 64x64 tile.
__device__ __forceinline__ bf16x8 rdz(const us16* buf, int row, int blk) {
  return *(const bf16x8*)&buf[row * 64 + ((blk ^ (row & 7)) * 8)];
}

// ---------------------------------------------------------------------------
// prep: fused (a) gate g[row]=sigmoid(query.gate_w+gate_b)   [blocks 0..1023]
//             (b) 6x weight transpose+cvt f32[k][n]->bf16[n][k] [1024..1407]
//             (c) query f32 -> bf16 (qb)                        [1408..1919]
// ---------------------------------------------------------------------------
struct WT6 {
  const float* src[6];
  us16* dst[6];
};
__global__ __launch_bounds__(256) void prep(WT6 p, const float* __restrict__ query,
    const float* __restrict__ gw, const float* __restrict__ gb,
    float* __restrict__ g, us16* __restrict__ qb) {
  __shared__ us16 T[64][72];
  int id = blockIdx.x;
  const int t = threadIdx.x;
  if (id < 1024) {
    int row = id * 4 + (t >> 6);
    int lane = t & 63;
    float pz = 0.f;
    for (int d = lane; d < D_; d += 64) pz += query[(size_t)row * D_ + d] * gw[d];
#pragma unroll
    for (int off = 32; off; off >>= 1) pz += __shfl_down(pz, off);
    if (lane == 0) g[row] = 1.f / (1.f + __expf(-(pz + gb[0])));
    return;
  }
  if (id >= 1408) {
    // query cvt: 4096 elems/block, 16/thread
    size_t base = (size_t)(id - 1408) * 4096 + t * 16;
    const float* src = query + base;
    union { bf16x8 v; us16 u[8]; } a0, a1;
#pragma unroll
    for (int j = 0; j < 8; ++j) { a0.u[j] = f2us(src[j]); a1.u[j] = f2us(src[8 + j]); }
    *(bf16x8*)&qb[base] = a0.v;
    *(bf16x8*)&qb[base + 8] = a1.v;
    return;
  }
  id -= 1024;
  const int z = id >> 6;
  const int k0 = ((id >> 3) & 7) * 64, n0 = (id & 7) * 64;
  const float* __restrict__ W = p.src[z];
  us16* __restrict__ Wt = p.dst[z];
  {
    int r = t >> 2, c = (t & 3) * 16;
    const float* src = W + (size_t)(k0 + r) * 512 + n0 + c;
    union { bf16x8 v; us16 u[8]; } p0, p1;
#pragma unroll
    for (int j = 0; j < 8; ++j) { p0.u[j] = f2us(src[j]); p1.u[j] = f2us(src[8 + j]); }
    *(bf16x8*)&T[r][c] = p0.v;
    *(bf16x8*)&T[r][c + 8] = p1.v;
  }
  __syncthreads();
  {
    int n = t >> 2, c = (t & 3) * 16;
    union { bf16x8 v; us16 u[8]; } p0, p1;
#pragma unroll
    for (int j = 0; j < 8; ++j) { p0.u[j] = T[c + j][n]; p1.u[j] = T[c + 8 + j][n]; }
    us16* dst = Wt + (size_t)(n0 + n) * 512 + k0 + c;
    *(bf16x8*)dst = p0.v;
    *(bf16x8*)(dst + 8) = p1.v;
  }
}

// gate standalone (fallback path only)
__global__ __launch_bounds__(256) void gate_kernel(
    const float* __restrict__ query, const float* __restrict__ gw,
    const float* __restrict__ gb, float* __restrict__ g) {
  int row = blockIdx.x * 4 + (threadIdx.x >> 6);
  int lane = threadIdx.x & 63;
  float p = 0.f;
  for (int d = lane; d < D_; d += 64) p += query[(size_t)row * D_ + d] * gw[d];
#pragma unroll
  for (int off = 32; off; off >>= 1) p += __shfl_down(p, off);
  if (lane == 0) g[row] = 1.f / (1.f + __expf(-(p + gb[0])));
}

// ---------------------------------------------------------------------------
// Batched projection GEMM, async-staged (validated round 10): 64x64 tile,
// BK=64, double-buffered linear LDS via global_load_lds + XOR swizzle, raw
// s_barrier + COUNTED vmcnt.  atype 1: A bf16 (DMA like B); atype 0: A f32
// reg-prefetch 1 buffer ahead + cvt + ds_write (wave-local rows).
// mode 1 (Vt) NOW transposes the output tile through LDS (reusing dead Abuf,
// wtrans6 pattern) -> coalesced 32B/thread row writes instead of 2KB-strided
// scalar scatter (was 64 lines per store instruction).
// XCD swizzle unchanged.  grid (8, 64, nz).
// ---------------------------------------------------------------------------
struct GJob {
  const float* A; const us16* Ab; const us16* Wt;
  const float* bias; us16* C; int mode; int atype;
};
struct GJobs { GJob j[3]; };

__global__ __launch_bounds__(256) void gemm3(GJobs jobs) {
  __shared__ us16 Abuf[2][64 * 64];
  __shared__ us16 Bbuf[2][64 * 64];
  int f = blockIdx.x + 8 * (blockIdx.y + 64 * blockIdx.z);
  const int cpx = 64 * (int)gridDim.z;           // nwg/8
  f = (f & 7) * cpx + (f >> 3);
  const int bx = f & 7, by = (f >> 3) & 63, bz = f >> 9;
  const GJob J = jobs.j[bz];
  const int tid = threadIdx.x;
  const int w = tid >> 6, lane = tid & 63;
  const int quad = lane >> 4, lc = lane & 15;
  const int row0 = by * 64, col0 = bx * 64;
  f32x4 acc[4] = {};

  const us16* Bg = J.Wt + (size_t)(col0 + w * 16) * 512;
  auto stgB = [&](int k, int cur) {
    stg8(Bg + k * 64, &Bbuf[cur][(w * 16) * 64], lane);
    stg8(Bg + 8 * 512 + k * 64, &Bbuf[cur][(w * 16 + 8) * 64], lane);
  };

  if (J.atype) {
    const us16* Ag = J.Ab + (size_t)(row0 + w * 16) * 512;
    auto stgA = [&](int k, int cur) {
      stg8(Ag + k * 64, &Abuf[cur][(w * 16) * 64], lane);
      stg8(Ag + 8 * 512 + k * 64, &Abuf[cur][(w * 16 + 8) * 64], lane);
    };
    stgA(0, 0); stgB(0, 0);
    stgA(1, 1); stgB(1, 1);
#pragma unroll
    for (int k = 0; k < 8; ++k) {
      const int cur = k & 1;
      if (k < 7) asm volatile("s_waitcnt vmcnt(4)" ::: "memory");
      else       asm volatile("s_waitcnt vmcnt(0)" ::: "memory");
      __builtin_amdgcn_sched_barrier(0);
      __builtin_amdgcn_s_barrier();
      __builtin_amdgcn_sched_barrier(0);
      bf16x8 a0 = rdz(Abuf[cur], w * 16 + lc, quad);
      bf16x8 a1 = rdz(Abuf[cur], w * 16 + lc, 4 + quad);
#pragma unroll
      for (int ct = 0; ct < 4; ++ct) {
        bf16x8 b0 = rdz(Bbuf[cur], ct * 16 + lc, quad);
        bf16x8 b1 = rdz(Bbuf[cur], ct * 16 + lc, 4 + quad);
        acc[ct] = MFMA(a0, b0, acc[ct]);
        acc[ct] = MFMA(a1, b1, acc[ct]);
      }
      __builtin_amdgcn_sched_barrier(0);
      __builtin_amdgcn_s_barrier();
      __builtin_amdgcn_sched_barrier(0);
      if (k + 2 < 8) { stgA(k + 2, cur); stgB(k + 2, cur); }
    }
  } else {
    const int fr = tid >> 2, j0 = (tid & 3) * 2;
    const float* arow = J.A + (size_t)(row0 + fr) * 512 + j0 * 8;
    f32x4 vA[4], vB[4];
    auto ldA = [&](int k, f32x4* v) {
      const float* p = arow + k * 64;
      v[0] = *(const f32x4*)(p);
      v[1] = *(const f32x4*)(p + 4);
      v[2] = *(const f32x4*)(p + 8);
      v[3] = *(const f32x4*)(p + 12);
    };
    auto wrA = [&](us16* abuf, const f32x4* v) {
      union { bf16x8 x; us16 u[8]; } p0, p1;
#pragma unroll
      for (int j = 0; j < 4; ++j) {
        p0.u[j] = f2us(v[0][j]); p0.u[4 + j] = f2us(v[1][j]);
        p1.u[j] = f2us(v[2][j]); p1.u[4 + j] = f2us(v[3][j]);
      }
      us16* wp = abuf + fr * 64;
      *(bf16x8*)&wp[(j0 ^ (fr & 7)) * 8] = p0.x;
      *(bf16x8*)&wp[((j0 + 1) ^ (fr & 7)) * 8] = p1.x;
    };
    ldA(0, vA); stgB(0, 0);
    ldA(1, vB); stgB(1, 1);
#pragma unroll
    for (int k = 0; k < 8; ++k) {
      const int cur = k & 1;
      if (k < 7) asm volatile("s_waitcnt vmcnt(6)" ::: "memory");
      else       asm volatile("s_waitcnt vmcnt(0)" ::: "memory");
      __builtin_amdgcn_sched_barrier(0);
      wrA(&Abuf[cur][0], cur ? vB : vA);
      asm volatile("s_waitcnt lgkmcnt(0)" ::: "memory");
      __builtin_amdgcn_sched_barrier(0);
      __builtin_amdgcn_s_barrier();
      __builtin_amdgcn_sched_barrier(0);
      bf16x8 a0 = rdz(Abuf[cur], w * 16 + lc, quad);
      bf16x8 a1 = rdz(Abuf[cur], w * 16 + lc, 4 + quad);
#pragma unroll
      for (int ct = 0; ct < 4; ++ct) {
        bf16x8 b0 = rdz(Bbuf[cur], ct * 16 + lc, quad);
        bf16x8 b1 = rdz(Bbuf[cur], ct * 16 + lc, 4 + quad);
        acc[ct] = MFMA(a0, b0, acc[ct]);
        acc[ct] = MFMA(a1, b1, acc[ct]);
      }
      __builtin_amdgcn_sched_barrier(0);
      __builtin_amdgcn_s_barrier();
      __builtin_amdgcn_sched_barrier(0);
      if (k + 2 < 8) { ldA(k + 2, cur ? vB : vA); stgB(k + 2, cur); }
    }
  }
  if (J.mode == 0) {
    const int orow = row0 + w * 16 + quad * 4;
#pragma unroll
    for (int ct = 0; ct < 4; ++ct) {
      const int col = col0 + ct * 16 + lc;
      const float bv = J.bias[col];
#pragma unroll
      for (int r = 0; r < 4; ++r)
        J.C[(size_t)(orow + r) * 512 + col] = f2us(acc[ct][r] + bv);
    }
  } else {
    // mode 1: transpose tile via LDS (Abuf is dead), coalesced Vt row writes.
    us16* T = &Abuf[0][0];   // used as [64][72]
    const int lr = w * 16 + quad * 4;   // local kv row base
#pragma unroll
    for (int ct = 0; ct < 4; ++ct) {
      const int col = col0 + ct * 16 + lc;
      const float bv = J.bias[col];
#pragma unroll
      for (int r = 0; r < 4; ++r)
        T[(lr + r) * 72 + ct * 16 + lc] = f2us(acc[ct][r] + bv);
    }
    __syncthreads();
    const int bb = row0 >> 10, kv0 = row0 & 1023, hh = col0 >> 6;
    const int n = tid >> 2, cc = (tid & 3) * 16;
    union { bf16x8 v; us16 u[8]; } p0, p1;
#pragma unroll
    for (int j = 0; j < 8; ++j) {
      p0.u[j] = T[(cc + j) * 72 + n];
      p1.u[j] = T[(cc + 8 + j) * 72 + n];
    }
    us16* dst = J.C + (((size_t)bb * H_ + hh) * DK_ + n) * L_ + kv0 + cc;
    *(bf16x8*)dst = p0.v;
    *(bf16x8*)(dst + 8) = p1.v;
  }
}

// ---------------------------------------------------------------------------
// Dense: C(f32) = A(bf16 ws) @ Wt(bf16 [n][k]) + bias.  Async-staged like
// gemm3 bf16 path.  64x64, BK=64, XCD swizzle.  grid (8, 64).
// ---------------------------------------------------------------------------
__global__ __launch_bounds__(256) void gemm_dense(
    const us16* __restrict__ A, const us16* __restrict__ Wt,
    const float* __restrict__ bias, float* __restrict__ C) {
  __shared__ us16 Abuf[2][64 * 64];
  __shared__ us16 Bbuf[2][64 * 64];
  int f = blockIdx.x + 8 * blockIdx.y;            // nwg = 512
  f = (f & 7) * 64 + (f >> 3);
  const int bx = f & 7, by = f >> 3;
  const int tid = threadIdx.x;
  const int w = tid >> 6, lane = tid & 63;
  const int quad = lane >> 4, lc = lane & 15;
  const int row0 = by * 64, col0 = bx * 64;
  f32x4 acc[4] = {};
  const us16* Ag = A + (size_t)(row0 + w * 16) * 512;
  const us16* Bg = Wt + (size_t)(col0 + w * 16) * 512;
  auto stg = [&](int k, int cur) {
    stg8(Ag + k * 64, &Abuf[cur][(w * 16) * 64], lane);
    stg8(Ag + 8 * 512 + k * 64, &Abuf[cur][(w * 16 + 8) * 64], lane);
    stg8(Bg + k * 64, &Bbuf[cur][(w * 16) * 64], lane);
    stg8(Bg + 8 * 512 + k * 64, &Bbuf[cur][(w * 16 + 8) * 64], lane);
  };
  stg(0, 0); stg(1, 1);
#pragma unroll
  for (int k = 0; k < 8; ++k) {
    const int cur = k & 1;
    if (k < 7) asm volatile("s_waitcnt vmcnt(4)" ::: "memory");
    else       asm volatile("s_waitcnt vmcnt(0)" ::: "memory");
    __builtin_amdgcn_sched_barrier(0);
    __builtin_amdgcn_s_barrier();
    __builtin_amdgcn_sched_barrier(0);
    bf16x8 a0 = rdz(Abuf[cur], w * 16 + lc, quad);
    bf16x8 a1 = rdz(Abuf[cur], w * 16 + lc, 4 + quad);
#pragma unroll
    for (int ct = 0; ct < 4; ++ct) {
      bf16x8 b0 = rdz(Bbuf[cur], ct * 16 + lc, quad);
      bf16x8 b1 = rdz(Bbuf[cur], ct * 16 + lc, 4 + quad);
      acc[ct] = MFMA(a0, b0, acc[ct]);
      acc[ct] = MFMA(a1, b1, acc[ct]);
    }
    __builtin_amdgcn_sched_barrier(0);
    __builtin_amdgcn_s_barrier();
    __builtin_amdgcn_sched_barrier(0);
    if (k + 2 < 8) stg(k + 2, cur);
  }
  const int orow = row0 + w * 16 + quad * 4;
#pragma unroll
  for (int ct = 0; ct < 4; ++ct) {
    const int col = col0 + ct * 16 + lc;
    const float bv = bias[col];
#pragma unroll
    for (int r = 0; r < 4; ++r)
      C[(size_t)(orow + r) * 512 + col] = acc[ct][r] + bv;
  }
}

// ---------------------------------------------------------------------------
// Mask: m = sigmoid(QP.KP^T / sqrt(512)) -> f32 out.  WK variant also writes
// wk = g + (1-g)*exp(1-m) bf16.  Async-staged (both operands bf16).
// 64x64 tile, BK=64, round-3 XCD swizzle.  grid (16, 16, B_).
// ---------------------------------------------------------------------------
template <bool WK>
__global__ __launch_bounds__(256) void mask16(
    const us16* __restrict__ QP, const us16* __restrict__ KP,
    float* __restrict__ Mout, const float* __restrict__ gbuf,
    us16* __restrict__ Wk) {
  __shared__ us16 Abuf[2][64 * 64];
  __shared__ us16 Bbuf[2][64 * 64];
  int f = blockIdx.x + 16 * (blockIdx.y + 16 * blockIdx.z);  // nwg = 1024
  f = (f & 7) * 128 + (f >> 3);
  const int bx = f & 15, by = (f >> 4) & 15, b = f >> 8;
  const int tid = threadIdx.x;
  const int w = tid >> 6, lane = tid & 63;
  const int quad = lane >> 4, lc = lane & 15;
  const int row0 = by * 64, col0 = bx * 64;
  f32x4 acc[4] = {};
  const us16* Ag = QP + (size_t)b * L_ * D_ + (size_t)(row0 + w * 16) * 512;
  const us16* Bg = KP + (size_t)b * L_ * D_ + (size_t)(col0 + w * 16) * 512;
  auto stg = [&](int k, int cur) {
    stg8(Ag + k * 64, &Abuf[cur][(w * 16) * 64], lane);
    stg8(Ag + 8 * 512 + k * 64, &Abuf[cur][(w * 16 + 8) * 64], lane);
    stg8(Bg + k * 64, &Bbuf[cur][(w * 16) * 64], lane);
    stg8(Bg + 8 * 512 + k * 64, &Bbuf[cur][(w * 16 + 8) * 64], lane);
  };
  stg(0, 0); stg(1, 1);
#pragma unroll
  for (int k = 0; k < 8; ++k) {
    const int cur = k & 1;
    if (k < 7) asm volatile("s_waitcnt vmcnt(4)" ::: "memory");
    else       asm volatile("s_waitcnt vmcnt(0)" ::: "memory");
    __builtin_amdgcn_sched_barrier(0);
    __builtin_amdgcn_s_barrier();
    __builtin_amdgcn_sched_barrier(0);
    bf16x8 a0 = rdz(Abuf[cur], w * 16 + lc, quad);
    bf16x8 a1 = rdz(Abuf[cur], w * 16 + lc, 4 + quad);
#pragma unroll
    for (int ct = 0; ct < 4; ++ct) {
      bf16x8 b0 = rdz(Bbuf[cur], ct * 16 + lc, quad);
      bf16x8 b1 = rdz(Bbuf[cur], ct * 16 + lc, 4 + quad);
      acc[ct] = MFMA(a0, b0, acc[ct]);
      acc[ct] = MFMA(a1, b1, acc[ct]);
    }
    __builtin_amdgcn_sched_barrier(0);
    __builtin_amdgcn_s_barrier();
    __builtin_amdgcn_sched_barrier(0);
    if (k + 2 < 8) stg(k + 2, cur);
  }
  const float sc2 = 0.04419417382415922f;  // 1/sqrt(512)
  const int orow = row0 + w * 16 + quad * 4;
  float gq[4];
  if (WK) {
#pragma unroll
    for (int r = 0; r < 4; ++r) gq[r] = gbuf[b * L_ + orow + r];
  }
#pragma unroll
  for (int ct = 0; ct < 4; ++ct) {
    const int col = col0 + ct * 16 + lc;
#pragma unroll
    for (int r = 0; r < 4; ++r) {
      float x = acc[ct][r] * sc2;
      float v = 1.f / (1.f + __expf(-x));
      size_t idx = ((size_t)b * L_ + orow + r) * L_ + col;
      Mout[idx] = v;
      if (WK) Wk[idx] = f2us(gq[r] + (1.f - gq[r]) * __expf(1.f - v));
    }
  }
}

// ---------------------------------------------------------------------------
// Attention v8 (round-10 validated, 51.7us — best measured): attn5 + 4-deep
// async K staging, counted vmcnt, XOR swizzle (source+read, linear dest).
// (attn9's explicit V-ring/Wk-batching regressed to 54us: compiler already
// pipelined those loads; occupancy dropped.  Reverted.)
// ---------------------------------------------------------------------------
__global__ __launch_bounds__(256, 4) void attn8(
    const us16* Qp, const us16* __restrict__ Kp,
    const us16* __restrict__ Vt, const us16* __restrict__ Wk, us16* O) {
  __shared__ us16 P[16 * 1032];   // pass1: [0,32KB) = K staging; pass2: P
  __shared__ float red[2][4][16];
  const int tid = threadIdx.x;
  const int w = tid >> 6, lane = tid & 63;
  const int quad = lane >> 4, lc = lane & 15;
  int raw = blockIdx.x + 64 * (blockIdx.y + 8 * blockIdx.z);
  const int c = raw & 7;
  const int rest = raw >> 3;            // [0,256)
  const int gg = c * 4 + (rest & 3);    // (b,h) combo; same -> same XCD
  const int q0 = (rest >> 2) * 16;
  const int h = gg & 7, b = gg >> 3;

  const us16* qptr = Qp + (size_t)(b * L_ + q0 + lc) * D_ + h * DK_;
  bf16x8 qa0 = *(const bf16x8*)(qptr + quad * 8);
  bf16x8 qa1 = *(const bf16x8*)(qptr + 32 + quad * 8);

  const us16* Kbase = Kp + (size_t)b * L_ * D_ + h * DK_;
  const int srow = lane >> 3;
  const int sblk = ((lane & 7) ^ srow) * 8;
  us16* kst = &P[w * 4096];

  auto stage = [&](int kt, int d) {
#pragma unroll
    for (int i = 0; i < 2; ++i) {
      const us16* src =
          Kbase + (size_t)(kt * 64 + w * 16 + i * 8 + srow) * D_ + sblk;
      __builtin_amdgcn_global_load_lds(
          (gas_u32)src, (las_u32)(kst + d * 1024 + i * 512), 16, 0, 0);
    }
  };

  const float c1 = 0.18033688011112042f;  // 0.125 * log2(e)

  stage(0, 0); stage(1, 1); stage(2, 2); stage(3, 3);

  float s[16][4];
  float sm[4] = {0.f, 0.f, 0.f, 0.f};
#pragma unroll
  for (int kt = 0; kt < 16; ++kt) {
    const int d = kt & 3;
    if (kt <= 12)      asm volatile("s_waitcnt vmcnt(6)" ::: "memory");
    else if (kt == 13) asm volatile("s_waitcnt vmcnt(4)" ::: "memory");
    else if (kt == 14) asm volatile("s_waitcnt vmcnt(2)" ::: "memory");
    else               asm volatile("s_waitcnt vmcnt(0)" ::: "memory");
    __builtin_amdgcn_sched_barrier(0);
    bf16x8 b0 = *(const bf16x8*)&kst[d * 1024 + lc * 64 + ((quad ^ (lc & 7)) * 8)];
    bf16x8 b1 = *(const bf16x8*)&kst[d * 1024 + lc * 64 + (((4 + quad) ^ (lc & 7)) * 8)];
    if (kt + 4 < 16) stage(kt + 4, d);
    f32x4 a = {};
    __builtin_amdgcn_s_setprio(1);
    a = MFMA(qa0, b0, a);
    a = MFMA(qa1, b1, a);
    __builtin_amdgcn_s_setprio(0);
#pragma unroll
    for (int r = 0; r < 4; ++r) {
      float e = fexp2(a[r] * c1);
      s[kt][r] = e;
      sm[r] += e;
    }
    __builtin_amdgcn_sched_barrier(0);
  }
#pragma unroll
  for (int r = 0; r < 4; ++r)
#pragma unroll
    for (int off = 1; off < 16; off <<= 1) sm[r] += __shfl_xor(sm[r], off);
  if (lc == 0)
#pragma unroll
    for (int r = 0; r < 4; ++r) red[0][w][quad * 4 + r] = sm[r];
  __syncthreads();
  float invr[4];  // log2(e) / sum1 (folds the 2nd-exp base conversion)
#pragma unroll
  for (int r = 0; r < 4; ++r) {
    const int row = quad * 4 + r;
    invr[r] = 1.44269504088896341f /
              (red[0][0][row] + red[0][1][row] + red[0][2][row] + red[0][3][row]);
  }

  const us16* wkb = Wk + (size_t)(b * L_ + q0 + quad * 4) * L_ + w * 16 + lc;
  float ts[4] = {0.f, 0.f, 0.f, 0.f};
#pragma unroll
  for (int kt = 0; kt < 16; ++kt) {
#pragma unroll
    for (int r = 0; r < 4; ++r) {
      float cv = s[kt][r] * invr[r] * us2f(wkb[(size_t)r * L_ + kt * 64]);
      float e2 = fexp2(cv);
      ts[r] += e2;
      P[(quad * 4 + r) * 1032 + kt * 64 + w * 16 + lc] = f2us(e2);
    }
  }
#pragma unroll
  for (int r = 0; r < 4; ++r)
#pragma unroll
    for (int off = 1; off < 16; off <<= 1) ts[r] += __shfl_xor(ts[r], off);
  if (lc == 0)
#pragma unroll
    for (int r = 0; r < 4; ++r) red[1][w][quad * 4 + r] = ts[r];
  __syncthreads();  // single barrier covers P writes AND red[1]

  const us16* Vb = Vt + ((size_t)(b * H_ + h) * DK_ + w * 16 + lc) * L_;
  f32x4 oacc = {};
  for (int kv = 0; kv < L_; kv += 32) {
    bf16x8 pa = *(const bf16x8*)&P[lc * 1032 + kv + quad * 8];
    bf16x8 vb = *(const bf16x8*)(Vb + kv + quad * 8);
    __builtin_amdgcn_s_setprio(1);
    oacc = MFMA(pa, vb, oacc);
    __builtin_amdgcn_s_setprio(0);
  }
#pragma unroll
  for (int r = 0; r < 4; ++r) {
    const int row = quad * 4 + r;
    float inv2 = 1.f /
        (red[1][0][row] + red[1][1][row] + red[1][2][row] + red[1][3][row]);
    O[(size_t)(b * L_ + q0 + row) * D_ + h * DK_ + w * 16 + lc] =
        f2us(oacc[r] * inv2);
  }
}

// ---------------------------------------------------------------------------
// Fallback kernels (small ws): round-8 path.
// ---------------------------------------------------------------------------
template <int MODE, typename TA>
__global__ __launch_bounds__(256) void gemm16(
    const TA* __restrict__ A, const float* __restrict__ W,
    const float* __restrict__ bias, void* __restrict__ Cout) {
  __shared__ us16 Al[64][56];
  __shared__ us16 Wl[64][56];
  const int tid = threadIdx.x;
  const int w = tid >> 6, lane = tid & 63;
  const int quad = lane >> 4, lc = lane & 15;
  const int row0 = blockIdx.y * 64, col0 = blockIdx.x * 64;
  f32x4 acc[4] = {};
  const int arow = tid >> 2, aks = (tid & 3) * 8;
  const int wk = tid & 31, wns = (tid >> 5) * 8;
  for (int k0 = 0; k0 < 512; k0 += 32) {
    {
      union { bf16x8 v; us16 u[8]; } pk;
      const TA* src = A + (size_t)(row0 + arow) * 512 + k0 + aks;
#pragma unroll
      for (int j = 0; j < 8; ++j) pk.u[j] = cvt_us(src[j]);
      *(bf16x8*)&Al[arow][aks] = pk.v;
    }
    {
      const float* src = W + (size_t)(k0 + wk) * 512 + col0 + wns;
#pragma unroll
      for (int j = 0; j < 8; ++j) Wl[wns + j][wk] = f2us(src[j]);
    }
    __syncthreads();
    bf16x8 af = *(const bf16x8*)&Al[w * 16 + lc][quad * 8];
#pragma unroll
    for (int ct = 0; ct < 4; ++ct) {
      bf16x8 bf = *(const bf16x8*)&Wl[ct * 16 + lc][quad * 8];
      acc[ct] = MFMA(af, bf, acc[ct]);
    }
    __syncthreads();
  }
  const int orow = row0 + w * 16 + quad * 4;
#pragma unroll
  for (int ct = 0; ct < 4; ++ct) {
    const int col = col0 + ct * 16 + lc;
    const float bv = bias[col];
    if (MODE == 0) {
      us16* C = (us16*)Cout;
#pragma unroll
      for (int r = 0; r < 4; ++r)
        C[(size_t)(orow + r) * 512 + col] = f2us(acc[ct][r] + bv);
    } else if (MODE == 1) {
      us16* C = (us16*)Cout;
      const int h = col >> 6, dk = col & 63;
#pragma unroll
      for (int r = 0; r < 4; ++r) {
        const int grow = orow + r;
        const int b = grow >> 10, kv = grow & 1023;
        C[(((size_t)b * H_ + h) * DK_ + dk) * L_ + kv] = f2us(acc[ct][r] + bv);
      }
    } else {
      float* C = (float*)Cout;
#pragma unroll
      for (int r = 0; r < 4; ++r)
        C[(size_t)(orow + r) * 512 + col] = acc[ct][r] + bv;
    }
  }
}

__global__ __launch_bounds__(256, 3) void attn2_fb(
    const us16* Qp, const us16* __restrict__ Kp,
    const us16* __restrict__ Vt, const float* __restrict__ Mm,
    const float* __restrict__ gbuf, us16* O) {
  __shared__ us16 Ql[16][72];
  __shared__ us16 P[16 * 1032];
  __shared__ float red[2][4][16];
  const int tid = threadIdx.x;
  const int w = tid >> 6, lane = tid & 63;
  const int quad = lane >> 4, lc = lane & 15;
  const int b = blockIdx.z, h = blockIdx.y, q0 = blockIdx.x * 16;
  if (tid < 128) {
    int r = tid >> 3, ks = (tid & 7) * 8;
    *(bf16x8*)&Ql[r][ks] =
        *(const bf16x8*)(Qp + (size_t)(b * L_ + q0 + r) * D_ + h * DK_ + ks);
  }
  __syncthreads();
  bf16x8 qa0 = *(const bf16x8*)&Ql[lc][quad * 8];
  bf16x8 qa1 = *(const bf16x8*)&Ql[lc][32 + quad * 8];
  const us16* Kbase = Kp + (size_t)b * L_ * D_ + h * DK_;
  float s[16][4];
#pragma unroll
  for (int kt = 0; kt < 16; ++kt) {
    const us16* kr = Kbase + (size_t)(kt * 64 + w * 16 + lc) * D_;
    bf16x8 b0 = *(const bf16x8*)(kr + quad * 8);
    bf16x8 b1 = *(const bf16x8*)(kr + 32 + quad * 8);
    f32x4 a = {};
    a = MFMA(qa0, b0, a);
    a = MFMA(qa1, b1, a);
#pragma unroll
    for (int r = 0; r < 4; ++r) s[kt][r] = a[r] * 0.125f;
  }
  float sm[4];
#pragma unroll
  for (int r = 0; r < 4; ++r) {
    float t = 0.f;
#pragma unroll
    for (int kt = 0; kt < 16; ++kt) { s[kt][r] = __expf(s[kt][r]); t += s[kt][r]; }
#pragma unroll
    for (int off = 1; off < 16; off <<= 1) t += __shfl_xor(t, off);
    sm[r] = t;
  }
  if (lc == 0)
#pragma unroll
    for (int r = 0; r < 4; ++r) red[0][w][quad * 4 + r] = sm[r];
  __syncthreads();
  float inv[4];
#pragma unroll
  for (int r = 0; r < 4; ++r) {
    const int row = quad * 4 + r;
    inv[r] = 1.f / (red[0][0][row] + red[0][1][row] + red[0][2][row] + red[0][3][row]);
  }
  float gq[4];
#pragma unroll
  for (int r = 0; r < 4; ++r) gq[r] = gbuf[b * L_ + q0 + quad * 4 + r];
#pragma unroll
  for (int r = 0; r < 4; ++r) {
    const float* mrow = Mm + (size_t)(b * L_ + q0 + quad * 4 + r) * L_;
    float t = 0.f;
#pragma unroll
    for (int kt = 0; kt < 16; ++kt) {
      float mval = mrow[kt * 64 + w * 16 + lc];
      float c = s[kt][r] * inv[r] * (gq[r] + (1.f - gq[r]) * __expf(1.f - mval));
      float e = __expf(c);
      s[kt][r] = e;
      t += e;
    }
#pragma unroll
    for (int off = 1; off < 16; off <<= 1) t += __shfl_xor(t, off);
    sm[r] = t;
  }
  if (lc == 0)
#pragma unroll
    for (int r = 0; r < 4; ++r) red[1][w][quad * 4 + r] = sm[r];
  __syncthreads();
#pragma unroll
  for (int r = 0; r < 4; ++r) {
    const int row = quad * 4 + r;
    inv[r] = 1.f / (red[1][0][row] + red[1][1][row] + red[1][2][row] + red[1][3][row]);
  }
#pragma unroll
  for (int kt = 0; kt < 16; ++kt)
#pragma unroll
    for (int r = 0; r < 4; ++r)
      P[(quad * 4 + r) * 1032 + kt * 64 + w * 16 + lc] = f2us(s[kt][r] * inv[r]);
  __syncthreads();
  const us16* Vb = Vt + (size_t)(b * H_ + h) * DK_ * L_;
  f32x4 oacc = {};
  for (int kv = 0; kv < L_; kv += 32) {
    bf16x8 pa = *(const bf16x8*)&P[lc * 1032 + kv + quad * 8];
    bf16x8 vb = *(const bf16x8*)(Vb + (size_t)(w * 16 + lc) * L_ + kv + quad * 8);
    oacc = MFMA(pa, vb, oacc);
  }
#pragma unroll
  for (int r = 0; r < 4; ++r)
    O[(size_t)(b * L_ + q0 + quad * 4 + r) * D_ + h * DK_ + w * 16 + lc] =
        f2us(oacc[r]);
}

extern "C" void kernel_launch(void* const* d_in, const int* in_sizes, int n_in,
                              void* d_out, int out_size, void* d_ws, size_t ws_size,
                              hipStream_t stream) {
  const float* query   = (const float*)d_in[0];
  const float* key     = (const float*)d_in[1];
  const float* value   = (const float*)d_in[2];
  const float* wq_w    = (const float*)d_in[3];
  const float* wq_b    = (const float*)d_in[4];
  const float* wk_w    = (const float*)d_in[5];
  const float* wk_b    = (const float*)d_in[6];
  const float* wv_w    = (const float*)d_in[7];
  const float* wv_b    = (const float*)d_in[8];
  const float* dense_w = (const float*)d_in[9];
  const float* dense_b = (const float*)d_in[10];
  const float* gate_w  = (const float*)d_in[11];
  const float* gate_b  = (const float*)d_in[12];
  const float* mp_wq_w = (const float*)d_in[13];
  const float* mp_wq_b = (const float*)d_in[14];
  const float* mp_wk_w = (const float*)d_in[15];
  const float* mp_wk_b = (const float*)d_in[16];

  const size_t RSZ = (size_t)BL_ * D_;   // 2,097,152 elems
  const size_t WSZ = (size_t)D_ * D_;    // 262,144 elems
  us16* R0 = (us16*)d_ws;                // 4 MB
  us16* R1 = R0 + RSZ;                   // 4 MB

  float* out0 = (float*)d_out;                 // final out f32 (8 MB)
  float* outm = out0 + (size_t)B_ * L_ * D_;   // m f32 (16 MB)
  us16*  Vt   = (us16*)d_out;                  // V^T bf16 in out bytes [0,4M)

  dim3 blk(256);

  if (ws_size >= ((size_t)20 << 20)) {
    // ws: R0(4M) R1(4M) Wt x6 (3M) Wk (8M) gbuf(16K) = 19.02 MB
    us16* Wt0 = R1 + RSZ;
    us16* mpq_t = Wt0;
    us16* mpk_t = Wt0 + WSZ;
    us16* wq_t  = Wt0 + 2 * WSZ;
    us16* wk_t  = Wt0 + 3 * WSZ;
    us16* wv_t  = Wt0 + 4 * WSZ;
    us16* dw_t  = Wt0 + 5 * WSZ;
    us16* Wk    = Wt0 + 6 * WSZ;                     // 8 MB
    float* gbuf = (float*)(Wk + (size_t)B_ * L_ * L_);  // 16 KB
    us16* qb = (us16*)((char*)d_out + (4u << 20));   // bf16 query, dead before dense

    WT6 wt;
    wt.src[0] = mp_wq_w; wt.dst[0] = mpq_t;
    wt.src[1] = mp_wk_w; wt.dst[1] = mpk_t;
    wt.src[2] = wq_w;    wt.dst[2] = wq_t;
    wt.src[3] = wk_w;    wt.dst[3] = wk_t;
    wt.src[4] = wv_w;    wt.dst[4] = wv_t;
    wt.src[5] = dense_w; wt.dst[5] = dw_t;
    hipLaunchKernelGGL(prep, dim3(1920), blk, 0, stream, wt, query, gate_w, gate_b, gbuf, qb);

    GJobs mp;
    mp.j[0] = { nullptr, qb, mpq_t, mp_wq_b, R0, 0, 1 };
    mp.j[1] = { key, nullptr, mpk_t, mp_wk_b, R1, 0, 0 };
    mp.j[2] = mp.j[1];
    hipLaunchKernelGGL(gemm3, dim3(8, 64, 2), blk, 0, stream, mp);
    hipLaunchKernelGGL(mask16<true>, dim3(16, 16, B_), blk, 0, stream,
                       R0, R1, outm, gbuf, Wk);

    GJobs qkv;
    qkv.j[0] = { nullptr, qb, wq_t, wq_b, R0, 0, 1 };
    qkv.j[1] = { key, nullptr, wk_t, wk_b, R1, 0, 0 };
    qkv.j[2] = { value, nullptr, wv_t, wv_b, Vt, 1, 0 };
    hipLaunchKernelGGL(gemm3, dim3(8, 64, 3), blk, 0, stream, qkv);

    hipLaunchKernelGGL(attn8, dim3(L_ / 16, H_, B_), blk, 0, stream, R0, R1, Vt, Wk, R0);
    hipLaunchKernelGGL(gemm_dense, dim3(8, 64), blk, 0, stream, R0, dw_t, dense_b, out0);
  } else {
    // -------- fallback (8 MB ws): round-8 structure --------
    float* gbuf = (float*)((char*)d_out + (4u << 20));
    dim3 gproj(8, 64);
    hipLaunchKernelGGL((gemm16<0, float>), gproj, blk, 0, stream, query, mp_wq_w, mp_wq_b, (void*)R0);
    hipLaunchKernelGGL((gemm16<0, float>), gproj, blk, 0, stream, key,   mp_wk_w, mp_wk_b, (void*)R1);
    hipLaunchKernelGGL(mask16<false>, dim3(16, 16, B_), blk, 0, stream,
                       R0, R1, outm, (const float*)nullptr, (us16*)nullptr);
    hipLaunchKernelGGL((gemm16<0, float>), gproj, blk, 0, stream, query, wq_w, wq_b, (void*)R0);
    hipLaunchKernelGGL((gemm16<0, float>), gproj, blk, 0, stream, key,   wk_w, wk_b, (void*)R1);
    hipLaunchKernelGGL((gemm16<1, float>), gproj, blk, 0, stream, value, wv_w, wv_b, (void*)Vt);
    hipLaunchKernelGGL(gate_kernel, dim3(BL_ / 4), blk, 0, stream, query, gate_w, gate_b, gbuf);
    hipLaunchKernelGGL(attn2_fb, dim3(L_ / 16, H_, B_), blk, 0, stream, R0, R1, Vt, outm, gbuf, R0);
    hipLaunchKernelGGL((gemm16<2, us16>), gproj, blk, 0, stream, R0, dense_w, dense_b, (void*)out0);
  }
}

// Round 14
// 206.658 us; speedup vs baseline: 1.0469x; 1.0469x over previous
//
#include <hip/hip_runtime.h>

#define B_  4
#define L_  1024
#define D_  512
#define H_  8
#define DK_ 64
#define BL_ (B_*L_)

typedef unsigned short us16;   // raw bf16 bits
typedef __attribute__((ext_vector_type(8))) short bf16x8;
typedef __attribute__((ext_vector_type(4))) float f32x4;

__device__ __forceinline__ float us2f(us16 u) {
  union { unsigned int i; float f; } x;
  x.i = ((unsigned int)u) << 16;
  return x.f;
}
__device__ __forceinline__ us16 f2us(float f) {
  union { float f; unsigned int i; } x;
  x.f = f;
  unsigned int r = x.i + 0x7FFFu + ((x.i >> 16) & 1u);  // RNE
  return (us16)(r >> 16);
}
__device__ __forceinline__ us16 cvt_us(float f) { return f2us(f); }
__device__ __forceinline__ us16 cvt_us(us16 u) { return u; }
// hardware base-2 exp (v_exp_f32); args here are bounded (|x| < ~8)
__device__ __forceinline__ float fexp2(float x) {
  return __builtin_amdgcn_exp2f(x);
}

#define MFMA(a, b, c) __builtin_amdgcn_mfma_f32_16x16x32_bf16(a, b, c, 0, 0, 0)

typedef const __attribute__((address_space(1))) unsigned int* gas_u32;
typedef __attribute__((address_space(3))) unsigned int* las_u32;

// ---- async tile staging helpers (attn8-validated pattern) ------------------
// stg8: DMA 8 rows x 128B from rowbase (ld=512 us16) into 1KB linear LDS.
// lane l: source row l>>3, source 16B-block (l&7)^(l>>3)  [XOR involution];
// dest = dst + l*16B (linear, HW-enforced).
__device__ __forceinline__ void stg8(const us16* rowbase, us16* dst, int lane) {
  const us16* src = rowbase + (size_t)(lane >> 3) * 512 +
                    (((lane & 7) ^ (lane >> 3)) * 8);
  __builtin_amdgcn_global_load_lds((gas_u32)src, (las_u32)dst, 16, 0, 0);
}
// rdz: read global 16B-block `blk` of row `row` from a swizzled 64x64 tile.
__device__ __forceinline__ bf16x8 rdz(const us16* buf, int row, int blk) {
  return *(const bf16x8*)&buf[row * 64 + ((blk ^ (row & 7)) * 8)];
}

// ---------------------------------------------------------------------------
// prep v2: fused (a) 6x weight transpose+cvt f32[k][n]->bf16[n][k] [0..383]
//                (b) query f32 -> bf16 (qb) PLUS gate (rows held in regs:
//                    32-thread group owns one 512-elem row; gate dot is
//                    16 FMAs + 5-level shfl tree)                 [384..895]
// Removes 1024 standalone gate blocks and a redundant 8MB query read.
// ---------------------------------------------------------------------------
struct WT6 {
  const float* src[6];
  us16* dst[6];
};
__global__ __launch_bounds__(256) void prep(WT6 p, const float* __restrict__ query,
    const float* __restrict__ gw, const float* __restrict__ gb,
    float* __restrict__ g, us16* __restrict__ qb) {
  __shared__ us16 T[64][72];
  int id = blockIdx.x;
  const int t = threadIdx.x;
  if (id >= 384) {
    // query cvt + gate: 4096 elems/block (8 rows), 16/thread
    const int cb = id - 384;
    size_t base = (size_t)cb * 4096 + t * 16;
    const float* src = query + base;
    float v[16];
#pragma unroll
    for (int j = 0; j < 16; ++j) v[j] = src[j];
    union { bf16x8 x; us16 u[8]; } a0, a1;
#pragma unroll
    for (int j = 0; j < 8; ++j) { a0.u[j] = f2us(v[j]); a1.u[j] = f2us(v[8 + j]); }
    *(bf16x8*)&qb[base] = a0.x;
    *(bf16x8*)&qb[base + 8] = a1.x;
    // gate: threads t..t|31 hold row cb*8 + (t>>5); dot with gw slice
    const int li = t & 31;
    float pz = 0.f;
#pragma unroll
    for (int j = 0; j < 16; ++j) pz += v[j] * gw[li * 16 + j];
#pragma unroll
    for (int off = 16; off; off >>= 1) pz += __shfl_xor(pz, off);
    if (li == 0) g[cb * 8 + (t >> 5)] = 1.f / (1.f + __expf(-(pz + gb[0])));
    return;
  }
  const int z = id >> 6;
  const int k0 = ((id >> 3) & 7) * 64, n0 = (id & 7) * 64;
  const float* __restrict__ W = p.src[z];
  us16* __restrict__ Wt = p.dst[z];
  {
    int r = t >> 2, c = (t & 3) * 16;
    const float* src = W + (size_t)(k0 + r) * 512 + n0 + c;
    union { bf16x8 v; us16 u[8]; } p0, p1;
#pragma unroll
    for (int j = 0; j < 8; ++j) { p0.u[j] = f2us(src[j]); p1.u[j] = f2us(src[8 + j]); }
    *(bf16x8*)&T[r][c] = p0.v;
    *(bf16x8*)&T[r][c + 8] = p1.v;
  }
  __syncthreads();
  {
    int n = t >> 2, c = (t & 3) * 16;
    union { bf16x8 v; us16 u[8]; } p0, p1;
#pragma unroll
    for (int j = 0; j < 8; ++j) { p0.u[j] = T[c + j][n]; p1.u[j] = T[c + 8 + j][n]; }
    us16* dst = Wt + (size_t)(n0 + n) * 512 + k0 + c;
    *(bf16x8*)dst = p0.v;
    *(bf16x8*)(dst + 8) = p1.v;
  }
}

// gate standalone (fallback path only)
__global__ __launch_bounds__(256) void gate_kernel(
    const float* __restrict__ query, const float* __restrict__ gw,
    const float* __restrict__ gb, float* __restrict__ g) {
  int row = blockIdx.x * 4 + (threadIdx.x >> 6);
  int lane = threadIdx.x & 63;
  float p = 0.f;
  for (int d = lane; d < D_; d += 64) p += query[(size_t)row * D_ + d] * gw[d];
#pragma unroll
  for (int off = 32; off; off >>= 1) p += __shfl_down(p, off);
  if (lane == 0) g[row] = 1.f / (1.f + __expf(-(p + gb[0])));
}

// ---------------------------------------------------------------------------
// Batched projection GEMM, async-staged (validated round 10): 64x64 tile,
// BK=64, double-buffered linear LDS via global_load_lds + XOR swizzle, raw
// s_barrier + COUNTED vmcnt.  atype 1: A bf16 (DMA like B); atype 0: A f32
// reg-prefetch 1 buffer ahead + cvt + ds_write (wave-local rows).
// mode 1 (Vt) transposes the output tile through LDS -> coalesced row writes.
// XCD swizzle unchanged.  grid (8, 64, nz).
// ---------------------------------------------------------------------------
struct GJob {
  const float* A; const us16* Ab; const us16* Wt;
  const float* bias; us16* C; int mode; int atype;
};
struct GJobs { GJob j[3]; };

__global__ __launch_bounds__(256) void gemm3(GJobs jobs) {
  __shared__ us16 Abuf[2][64 * 64];
  __shared__ us16 Bbuf[2][64 * 64];
  int f = blockIdx.x + 8 * (blockIdx.y + 64 * blockIdx.z);
  const int cpx = 64 * (int)gridDim.z;           // nwg/8
  f = (f & 7) * cpx + (f >> 3);
  const int bx = f & 7, by = (f >> 3) & 63, bz = f >> 9;
  const GJob J = jobs.j[bz];
  const int tid = threadIdx.x;
  const int w = tid >> 6, lane = tid & 63;
  const int quad = lane >> 4, lc = lane & 15;
  const int row0 = by * 64, col0 = bx * 64;
  f32x4 acc[4] = {};

  const us16* Bg = J.Wt + (size_t)(col0 + w * 16) * 512;
  auto stgB = [&](int k, int cur) {
    stg8(Bg + k * 64, &Bbuf[cur][(w * 16) * 64], lane);
    stg8(Bg + 8 * 512 + k * 64, &Bbuf[cur][(w * 16 + 8) * 64], lane);
  };

  if (J.atype) {
    const us16* Ag = J.Ab + (size_t)(row0 + w * 16) * 512;
    auto stgA = [&](int k, int cur) {
      stg8(Ag + k * 64, &Abuf[cur][(w * 16) * 64], lane);
      stg8(Ag + 8 * 512 + k * 64, &Abuf[cur][(w * 16 + 8) * 64], lane);
    };
    stgA(0, 0); stgB(0, 0);
    stgA(1, 1); stgB(1, 1);
#pragma unroll
    for (int k = 0; k < 8; ++k) {
      const int cur = k & 1;
      if (k < 7) asm volatile("s_waitcnt vmcnt(4)" ::: "memory");
      else       asm volatile("s_waitcnt vmcnt(0)" ::: "memory");
      __builtin_amdgcn_sched_barrier(0);
      __builtin_amdgcn_s_barrier();
      __builtin_amdgcn_sched_barrier(0);
      bf16x8 a0 = rdz(Abuf[cur], w * 16 + lc, quad);
      bf16x8 a1 = rdz(Abuf[cur], w * 16 + lc, 4 + quad);
#pragma unroll
      for (int ct = 0; ct < 4; ++ct) {
        bf16x8 b0 = rdz(Bbuf[cur], ct * 16 + lc, quad);
        bf16x8 b1 = rdz(Bbuf[cur], ct * 16 + lc, 4 + quad);
        acc[ct] = MFMA(a0, b0, acc[ct]);
        acc[ct] = MFMA(a1, b1, acc[ct]);
      }
      __builtin_amdgcn_sched_barrier(0);
      __builtin_amdgcn_s_barrier();
      __builtin_amdgcn_sched_barrier(0);
      if (k + 2 < 8) { stgA(k + 2, cur); stgB(k + 2, cur); }
    }
  } else {
    const int fr = tid >> 2, j0 = (tid & 3) * 2;
    const float* arow = J.A + (size_t)(row0 + fr) * 512 + j0 * 8;
    f32x4 vA[4], vB[4];
    auto ldA = [&](int k, f32x4* v) {
      const float* p = arow + k * 64;
      v[0] = *(const f32x4*)(p);
      v[1] = *(const f32x4*)(p + 4);
      v[2] = *(const f32x4*)(p + 8);
      v[3] = *(const f32x4*)(p + 12);
    };
    auto wrA = [&](us16* abuf, const f32x4* v) {
      union { bf16x8 x; us16 u[8]; } p0, p1;
#pragma unroll
      for (int j = 0; j < 4; ++j) {
        p0.u[j] = f2us(v[0][j]); p0.u[4 + j] = f2us(v[1][j]);
        p1.u[j] = f2us(v[2][j]); p1.u[4 + j] = f2us(v[3][j]);
      }
      us16* wp = abuf + fr * 64;
      *(bf16x8*)&wp[(j0 ^ (fr & 7)) * 8] = p0.x;
      *(bf16x8*)&wp[((j0 + 1) ^ (fr & 7)) * 8] = p1.x;
    };
    ldA(0, vA); stgB(0, 0);
    ldA(1, vB); stgB(1, 1);
#pragma unroll
    for (int k = 0; k < 8; ++k) {
      const int cur = k & 1;
      if (k < 7) asm volatile("s_waitcnt vmcnt(6)" ::: "memory");
      else       asm volatile("s_waitcnt vmcnt(0)" ::: "memory");
      __builtin_amdgcn_sched_barrier(0);
      wrA(&Abuf[cur][0], cur ? vB : vA);
      asm volatile("s_waitcnt lgkmcnt(0)" ::: "memory");
      __builtin_amdgcn_sched_barrier(0);
      __builtin_amdgcn_s_barrier();
      __builtin_amdgcn_sched_barrier(0);
      bf16x8 a0 = rdz(Abuf[cur], w * 16 + lc, quad);
      bf16x8 a1 = rdz(Abuf[cur], w * 16 + lc, 4 + quad);
#pragma unroll
      for (int ct = 0; ct < 4; ++ct) {
        bf16x8 b0 = rdz(Bbuf[cur], ct * 16 + lc, quad);
        bf16x8 b1 = rdz(Bbuf[cur], ct * 16 + lc, 4 + quad);
        acc[ct] = MFMA(a0, b0, acc[ct]);
        acc[ct] = MFMA(a1, b1, acc[ct]);
      }
      __builtin_amdgcn_sched_barrier(0);
      __builtin_amdgcn_s_barrier();
      __builtin_amdgcn_sched_barrier(0);
      if (k + 2 < 8) { ldA(k + 2, cur ? vB : vA); stgB(k + 2, cur); }
    }
  }
  if (J.mode == 0) {
    const int orow = row0 + w * 16 + quad * 4;
#pragma unroll
    for (int ct = 0; ct < 4; ++ct) {
      const int col = col0 + ct * 16 + lc;
      const float bv = J.bias[col];
#pragma unroll
      for (int r = 0; r < 4; ++r)
        J.C[(size_t)(orow + r) * 512 + col] = f2us(acc[ct][r] + bv);
    }
  } else {
    // mode 1: transpose tile via LDS (Abuf is dead), coalesced Vt row writes.
    us16* T = &Abuf[0][0];   // used as [64][72]
    const int lr = w * 16 + quad * 4;   // local kv row base
#pragma unroll
    for (int ct = 0; ct < 4; ++ct) {
      const int col = col0 + ct * 16 + lc;
      const float bv = J.bias[col];
#pragma unroll
      for (int r = 0; r < 4; ++r)
        T[(lr + r) * 72 + ct * 16 + lc] = f2us(acc[ct][r] + bv);
    }
    __syncthreads();
    const int bb = row0 >> 10, kv0 = row0 & 1023, hh = col0 >> 6;
    const int n = tid >> 2, cc = (tid & 3) * 16;
    union { bf16x8 v; us16 u[8]; } p0, p1;
#pragma unroll
    for (int j = 0; j < 8; ++j) {
      p0.u[j] = T[(cc + j) * 72 + n];
      p1.u[j] = T[(cc + 8 + j) * 72 + n];
    }
    us16* dst = J.C + (((size_t)bb * H_ + hh) * DK_ + n) * L_ + kv0 + cc;
    *(bf16x8*)dst = p0.v;
    *(bf16x8*)(dst + 8) = p1.v;
  }
}

// ---------------------------------------------------------------------------
// Dense: C(f32) = A(bf16 ws) @ Wt(bf16 [n][k]) + bias.  Async-staged like
// gemm3 bf16 path.  64x64, BK=64, XCD swizzle.  grid (8, 64).
// ---------------------------------------------------------------------------
__global__ __launch_bounds__(256) void gemm_dense(
    const us16* __restrict__ A, const us16* __restrict__ Wt,
    const float* __restrict__ bias, float* __restrict__ C) {
  __shared__ us16 Abuf[2][64 * 64];
  __shared__ us16 Bbuf[2][64 * 64];
  int f = blockIdx.x + 8 * blockIdx.y;            // nwg = 512
  f = (f & 7) * 64 + (f >> 3);
  const int bx = f & 7, by = f >> 3;
  const int tid = threadIdx.x;
  const int w = tid >> 6, lane = tid & 63;
  const int quad = lane >> 4, lc = lane & 15;
  const int row0 = by * 64, col0 = bx * 64;
  f32x4 acc[4] = {};
  const us16* Ag = A + (size_t)(row0 + w * 16) * 512;
  const us16* Bg = Wt + (size_t)(col0 + w * 16) * 512;
  auto stg = [&](int k, int cur) {
    stg8(Ag + k * 64, &Abuf[cur][(w * 16) * 64], lane);
    stg8(Ag + 8 * 512 + k * 64, &Abuf[cur][(w * 16 + 8) * 64], lane);
    stg8(Bg + k * 64, &Bbuf[cur][(w * 16) * 64], lane);
    stg8(Bg + 8 * 512 + k * 64, &Bbuf[cur][(w * 16 + 8) * 64], lane);
  };
  stg(0, 0); stg(1, 1);
#pragma unroll
  for (int k = 0; k < 8; ++k) {
    const int cur = k & 1;
    if (k < 7) asm volatile("s_waitcnt vmcnt(4)" ::: "memory");
    else       asm volatile("s_waitcnt vmcnt(0)" ::: "memory");
    __builtin_amdgcn_sched_barrier(0);
    __builtin_amdgcn_s_barrier();
    __builtin_amdgcn_sched_barrier(0);
    bf16x8 a0 = rdz(Abuf[cur], w * 16 + lc, quad);
    bf16x8 a1 = rdz(Abuf[cur], w * 16 + lc, 4 + quad);
#pragma unroll
    for (int ct = 0; ct < 4; ++ct) {
      bf16x8 b0 = rdz(Bbuf[cur], ct * 16 + lc, quad);
      bf16x8 b1 = rdz(Bbuf[cur], ct * 16 + lc, 4 + quad);
      acc[ct] = MFMA(a0, b0, acc[ct]);
      acc[ct] = MFMA(a1, b1, acc[ct]);
    }
    __builtin_amdgcn_sched_barrier(0);
    __builtin_amdgcn_s_barrier();
    __builtin_amdgcn_sched_barrier(0);
    if (k + 2 < 8) stg(k + 2, cur);
  }
  const int orow = row0 + w * 16 + quad * 4;
#pragma unroll
  for (int ct = 0; ct < 4; ++ct) {
    const int col = col0 + ct * 16 + lc;
    const float bv = bias[col];
#pragma unroll
    for (int r = 0; r < 4; ++r)
      C[(size_t)(orow + r) * 512 + col] = acc[ct][r] + bv;
  }
}

// ---------------------------------------------------------------------------
// Mask: m = sigmoid(QP.KP^T / sqrt(512)) -> f32 out.  WK variant also writes
// wk = g + (1-g)*exp(1-m) bf16.  Async-staged (both operands bf16).
// 64x64 tile, BK=64, round-3 XCD swizzle.  grid (16, 16, B_).
// ---------------------------------------------------------------------------
template <bool WK>
__global__ __launch_bounds__(256) void mask16(
    const us16* __restrict__ QP, const us16* __restrict__ KP,
    float* __restrict__ Mout, const float* __restrict__ gbuf,
    us16* __restrict__ Wk) {
  __shared__ us16 Abuf[2][64 * 64];
  __shared__ us16 Bbuf[2][64 * 64];
  int f = blockIdx.x + 16 * (blockIdx.y + 16 * blockIdx.z);  // nwg = 1024
  f = (f & 7) * 128 + (f >> 3);
  const int bx = f & 15, by = (f >> 4) & 15, b = f >> 8;
  const int tid = threadIdx.x;
  const int w = tid >> 6, lane = tid & 63;
  const int quad = lane >> 4, lc = lane & 15;
  const int row0 = by * 64, col0 = bx * 64;
  f32x4 acc[4] = {};
  const us16* Ag = QP + (size_t)b * L_ * D_ + (size_t)(row0 + w * 16) * 512;
  const us16* Bg = KP + (size_t)b * L_ * D_ + (size_t)(col0 + w * 16) * 512;
  auto stg = [&](int k, int cur) {
    stg8(Ag + k * 64, &Abuf[cur][(w * 16) * 64], lane);
    stg8(Ag + 8 * 512 + k * 64, &Abuf[cur][(w * 16 + 8) * 64], lane);
    stg8(Bg + k * 64, &Bbuf[cur][(w * 16) * 64], lane);
    stg8(Bg + 8 * 512 + k * 64, &Bbuf[cur][(w * 16 + 8) * 64], lane);
  };
  stg(0, 0); stg(1, 1);
#pragma unroll
  for (int k = 0; k < 8; ++k) {
    const int cur = k & 1;
    if (k < 7) asm volatile("s_waitcnt vmcnt(4)" ::: "memory");
    else       asm volatile("s_waitcnt vmcnt(0)" ::: "memory");
    __builtin_amdgcn_sched_barrier(0);
    __builtin_amdgcn_s_barrier();
    __builtin_amdgcn_sched_barrier(0);
    bf16x8 a0 = rdz(Abuf[cur], w * 16 + lc, quad);
    bf16x8 a1 = rdz(Abuf[cur], w * 16 + lc, 4 + quad);
#pragma unroll
    for (int ct = 0; ct < 4; ++ct) {
      bf16x8 b0 = rdz(Bbuf[cur], ct * 16 + lc, quad);
      bf16x8 b1 = rdz(Bbuf[cur], ct * 16 + lc, 4 + quad);
      acc[ct] = MFMA(a0, b0, acc[ct]);
      acc[ct] = MFMA(a1, b1, acc[ct]);
    }
    __builtin_amdgcn_sched_barrier(0);
    __builtin_amdgcn_s_barrier();
    __builtin_amdgcn_sched_barrier(0);
    if (k + 2 < 8) stg(k + 2, cur);
  }
  const float sc2 = 0.04419417382415922f;  // 1/sqrt(512)
  const int orow = row0 + w * 16 + quad * 4;
  float gq[4];
  if (WK) {
#pragma unroll
    for (int r = 0; r < 4; ++r) gq[r] = gbuf[b * L_ + orow + r];
  }
#pragma unroll
  for (int ct = 0; ct < 4; ++ct) {
    const int col = col0 + ct * 16 + lc;
#pragma unroll
    for (int r = 0; r < 4; ++r) {
      float x = acc[ct][r] * sc2;
      float v = 1.f / (1.f + __expf(-x));
      size_t idx = ((size_t)b * L_ + orow + r) * L_ + col;
      Mout[idx] = v;
      if (WK) Wk[idx] = f2us(gq[r] + (1.f - gq[r]) * __expf(1.f - v));
    }
  }
}

// ---------------------------------------------------------------------------
// Attention v8 (validated best: 51.7us r10; cross-round noise 52-62us):
// attn5 + 4-deep async K staging, counted vmcnt, XOR swizzle.
// ---------------------------------------------------------------------------
__global__ __launch_bounds__(256, 4) void attn8(
    const us16* Qp, const us16* __restrict__ Kp,
    const us16* __restrict__ Vt, const us16* __restrict__ Wk, us16* O) {
  __shared__ us16 P[16 * 1032];   // pass1: [0,32KB) = K staging; pass2: P
  __shared__ float red[2][4][16];
  const int tid = threadIdx.x;
  const int w = tid >> 6, lane = tid & 63;
  const int quad = lane >> 4, lc = lane & 15;
  int raw = blockIdx.x + 64 * (blockIdx.y + 8 * blockIdx.z);
  const int c = raw & 7;
  const int rest = raw >> 3;            // [0,256)
  const int gg = c * 4 + (rest & 3);    // (b,h) combo; same -> same XCD
  const int q0 = (rest >> 2) * 16;
  const int h = gg & 7, b = gg >> 3;

  const us16* qptr = Qp + (size_t)(b * L_ + q0 + lc) * D_ + h * DK_;
  bf16x8 qa0 = *(const bf16x8*)(qptr + quad * 8);
  bf16x8 qa1 = *(const bf16x8*)(qptr + 32 + quad * 8);

  const us16* Kbase = Kp + (size_t)b * L_ * D_ + h * DK_;
  const int srow = lane >> 3;
  const int sblk = ((lane & 7) ^ srow) * 8;
  us16* kst = &P[w * 4096];

  auto stage = [&](int kt, int d) {
#pragma unroll
    for (int i = 0; i < 2; ++i) {
      const us16* src =
          Kbase + (size_t)(kt * 64 + w * 16 + i * 8 + srow) * D_ + sblk;
      __builtin_amdgcn_global_load_lds(
          (gas_u32)src, (las_u32)(kst + d * 1024 + i * 512), 16, 0, 0);
    }
  };

  const float c1 = 0.18033688011112042f;  // 0.125 * log2(e)

  stage(0, 0); stage(1, 1); stage(2, 2); stage(3, 3);

  float s[16][4];
  float sm[4] = {0.f, 0.f, 0.f, 0.f};
#pragma unroll
  for (int kt = 0; kt < 16; ++kt) {
    const int d = kt & 3;
    if (kt <= 12)      asm volatile("s_waitcnt vmcnt(6)" ::: "memory");
    else if (kt == 13) asm volatile("s_waitcnt vmcnt(4)" ::: "memory");
    else if (kt == 14) asm volatile("s_waitcnt vmcnt(2)" ::: "memory");
    else               asm volatile("s_waitcnt vmcnt(0)" ::: "memory");
    __builtin_amdgcn_sched_barrier(0);
    bf16x8 b0 = *(const bf16x8*)&kst[d * 1024 + lc * 64 + ((quad ^ (lc & 7)) * 8)];
    bf16x8 b1 = *(const bf16x8*)&kst[d * 1024 + lc * 64 + (((4 + quad) ^ (lc & 7)) * 8)];
    if (kt + 4 < 16) stage(kt + 4, d);
    f32x4 a = {};
    __builtin_amdgcn_s_setprio(1);
    a = MFMA(qa0, b0, a);
    a = MFMA(qa1, b1, a);
    __builtin_amdgcn_s_setprio(0);
#pragma unroll
    for (int r = 0; r < 4; ++r) {
      float e = fexp2(a[r] * c1);
      s[kt][r] = e;
      sm[r] += e;
    }
    __builtin_amdgcn_sched_barrier(0);
  }
#pragma unroll
  for (int r = 0; r < 4; ++r)
#pragma unroll
    for (int off = 1; off < 16; off <<= 1) sm[r] += __shfl_xor(sm[r], off);
  if (lc == 0)
#pragma unroll
    for (int r = 0; r < 4; ++r) red[0][w][quad * 4 + r] = sm[r];
  __syncthreads();
  float invr[4];  // log2(e) / sum1 (folds the 2nd-exp base conversion)
#pragma unroll
  for (int r = 0; r < 4; ++r) {
    const int row = quad * 4 + r;
    invr[r] = 1.44269504088896341f /
              (red[0][0][row] + red[0][1][row] + red[0][2][row] + red[0][3][row]);
  }

  const us16* wkb = Wk + (size_t)(b * L_ + q0 + quad * 4) * L_ + w * 16 + lc;
  float ts[4] = {0.f, 0.f, 0.f, 0.f};
#pragma unroll
  for (int kt = 0; kt < 16; ++kt) {
#pragma unroll
    for (int r = 0; r < 4; ++r) {
      float cv = s[kt][r] * invr[r] * us2f(wkb[(size_t)r * L_ + kt * 64]);
      float e2 = fexp2(cv);
      ts[r] += e2;
      P[(quad * 4 + r) * 1032 + kt * 64 + w * 16 + lc] = f2us(e2);
    }
  }
#pragma unroll
  for (int r = 0; r < 4; ++r)
#pragma unroll
    for (int off = 1; off < 16; off <<= 1) ts[r] += __shfl_xor(ts[r], off);
  if (lc == 0)
#pragma unroll
    for (int r = 0; r < 4; ++r) red[1][w][quad * 4 + r] = ts[r];
  __syncthreads();  // single barrier covers P writes AND red[1]

  const us16* Vb = Vt + ((size_t)(b * H_ + h) * DK_ + w * 16 + lc) * L_;
  f32x4 oacc = {};
  for (int kv = 0; kv < L_; kv += 32) {
    bf16x8 pa = *(const bf16x8*)&P[lc * 1032 + kv + quad * 8];
    bf16x8 vb = *(const bf16x8*)(Vb + kv + quad * 8);
    __builtin_amdgcn_s_setprio(1);
    oacc = MFMA(pa, vb, oacc);
    __builtin_amdgcn_s_setprio(0);
  }
#pragma unroll
  for (int r = 0; r < 4; ++r) {
    const int row = quad * 4 + r;
    float inv2 = 1.f /
        (red[1][0][row] + red[1][1][row] + red[1][2][row] + red[1][3][row]);
    O[(size_t)(b * L_ + q0 + row) * D_ + h * DK_ + w * 16 + lc] =
        f2us(oacc[r] * inv2);
  }
}

// ---------------------------------------------------------------------------
// Fallback kernels (small ws): round-8 path.
// ---------------------------------------------------------------------------
template <int MODE, typename TA>
__global__ __launch_bounds__(256) void gemm16(
    const TA* __restrict__ A, const float* __restrict__ W,
    const float* __restrict__ bias, void* __restrict__ Cout) {
  __shared__ us16 Al[64][56];
  __shared__ us16 Wl[64][56];
  const int tid = threadIdx.x;
  const int w = tid >> 6, lane = tid & 63;
  const int quad = lane >> 4, lc = lane & 15;
  const int row0 = blockIdx.y * 64, col0 = blockIdx.x * 64;
  f32x4 acc[4] = {};
  const int arow = tid >> 2, aks = (tid & 3) * 8;
  const int wk = tid & 31, wns = (tid >> 5) * 8;
  for (int k0 = 0; k0 < 512; k0 += 32) {
    {
      union { bf16x8 v; us16 u[8]; } pk;
      const TA* src = A + (size_t)(row0 + arow) * 512 + k0 + aks;
#pragma unroll
      for (int j = 0; j < 8; ++j) pk.u[j] = cvt_us(src[j]);
      *(bf16x8*)&Al[arow][aks] = pk.v;
    }
    {
      const float* src = W + (size_t)(k0 + wk) * 512 + col0 + wns;
#pragma unroll
      for (int j = 0; j < 8; ++j) Wl[wns + j][wk] = f2us(src[j]);
    }
    __syncthreads();
    bf16x8 af = *(const bf16x8*)&Al[w * 16 + lc][quad * 8];
#pragma unroll
    for (int ct = 0; ct < 4; ++ct) {
      bf16x8 bf = *(const bf16x8*)&Wl[ct * 16 + lc][quad * 8];
      acc[ct] = MFMA(af, bf, acc[ct]);
    }
    __syncthreads();
  }
  const int orow = row0 + w * 16 + quad * 4;
#pragma unroll
  for (int ct = 0; ct < 4; ++ct) {
    const int col = col0 + ct * 16 + lc;
    const float bv = bias[col];
    if (MODE == 0) {
      us16* C = (us16*)Cout;
#pragma unroll
      for (int r = 0; r < 4; ++r)
        C[(size_t)(orow + r) * 512 + col] = f2us(acc[ct][r] + bv);
    } else if (MODE == 1) {
      us16* C = (us16*)Cout;
      const int h = col >> 6, dk = col & 63;
#pragma unroll
      for (int r = 0; r < 4; ++r) {
        const int grow = orow + r;
        const int b = grow >> 10, kv = grow & 1023;
        C[(((size_t)b * H_ + h) * DK_ + dk) * L_ + kv] = f2us(acc[ct][r] + bv);
      }
    } else {
      float* C = (float*)Cout;
#pragma unroll
      for (int r = 0; r < 4; ++r)
        C[(size_t)(orow + r) * 512 + col] = acc[ct][r] + bv;
    }
  }
}

__global__ __launch_bounds__(256, 3) void attn2_fb(
    const us16* Qp, const us16* __restrict__ Kp,
    const us16* __restrict__ Vt, const float* __restrict__ Mm,
    const float* __restrict__ gbuf, us16* O) {
  __shared__ us16 Ql[16][72];
  __shared__ us16 P[16 * 1032];
  __shared__ float red[2][4][16];
  const int tid = threadIdx.x;
  const int w = tid >> 6, lane = tid & 63;
  const int quad = lane >> 4, lc = lane & 15;
  const int b = blockIdx.z, h = blockIdx.y, q0 = blockIdx.x * 16;
  if (tid < 128) {
    int r = tid >> 3, ks = (tid & 7) * 8;
    *(bf16x8*)&Ql[r][ks] =
        *(const bf16x8*)(Qp + (size_t)(b * L_ + q0 + r) * D_ + h * DK_ + ks);
  }
  __syncthreads();
  bf16x8 qa0 = *(const bf16x8*)&Ql[lc][quad * 8];
  bf16x8 qa1 = *(const bf16x8*)&Ql[lc][32 + quad * 8];
  const us16* Kbase = Kp + (size_t)b * L_ * D_ + h * DK_;
  float s[16][4];
#pragma unroll
  for (int kt = 0; kt < 16; ++kt) {
    const us16* kr = Kbase + (size_t)(kt * 64 + w * 16 + lc) * D_;
    bf16x8 b0 = *(const bf16x8*)(kr + quad * 8);
    bf16x8 b1 = *(const bf16x8*)(kr + 32 + quad * 8);
    f32x4 a = {};
    a = MFMA(qa0, b0, a);
    a = MFMA(qa1, b1, a);
#pragma unroll
    for (int r = 0; r < 4; ++r) s[kt][r] = a[r] * 0.125f;
  }
  float sm[4];
#pragma unroll
  for (int r = 0; r < 4; ++r) {
    float t = 0.f;
#pragma unroll
    for (int kt = 0; kt < 16; ++kt) { s[kt][r] = __expf(s[kt][r]); t += s[kt][r]; }
#pragma unroll
    for (int off = 1; off < 16; off <<= 1) t += __shfl_xor(t, off);
    sm[r] = t;
  }
  if (lc == 0)
#pragma unroll
    for (int r = 0; r < 4; ++r) red[0][w][quad * 4 + r] = sm[r];
  __syncthreads();
  float inv[4];
#pragma unroll
  for (int r = 0; r < 4; ++r) {
    const int row = quad * 4 + r;
    inv[r] = 1.f / (red[0][0][row] + red[0][1][row] + red[0][2][row] + red[0][3][row]);
  }
  float gq[4];
#pragma unroll
  for (int r = 0; r < 4; ++r) gq[r] = gbuf[b * L_ + q0 + quad * 4 + r];
#pragma unroll
  for (int r = 0; r < 4; ++r) {
    const float* mrow = Mm + (size_t)(b * L_ + q0 + quad * 4 + r) * L_;
    float t = 0.f;
#pragma unroll
    for (int kt = 0; kt < 16; ++kt) {
      float mval = mrow[kt * 64 + w * 16 + lc];
      float c = s[kt][r] * inv[r] * (gq[r] + (1.f - gq[r]) * __expf(1.f - mval));
      float e = __expf(c);
      s[kt][r] = e;
      t += e;
    }
#pragma unroll
    for (int off = 1; off < 16; off <<= 1) t += __shfl_xor(t, off);
    sm[r] = t;
  }
  if (lc == 0)
#pragma unroll
    for (int r = 0; r < 4; ++r) red[1][w][quad * 4 + r] = sm[r];
  __syncthreads();
#pragma unroll
  for (int r = 0; r < 4; ++r) {
    const int row = quad * 4 + r;
    inv[r] = 1.f / (red[1][0][row] + red[1][1][row] + red[1][2][row] + red[1][3][row]);
  }
#pragma unroll
  for (int kt = 0; kt < 16; ++kt)
#pragma unroll
    for (int r = 0; r < 4; ++r)
      P[(quad * 4 + r) * 1032 + kt * 64 + w * 16 + lc] = f2us(s[kt][r] * inv[r]);
  __syncthreads();
  const us16* Vb = Vt + (size_t)(b * H_ + h) * DK_ * L_;
  f32x4 oacc = {};
  for (int kv = 0; kv < L_; kv += 32) {
    bf16x8 pa = *(const bf16x8*)&P[lc * 1032 + kv + quad * 8];
    bf16x8 vb = *(const bf16x8*)(Vb + (size_t)(w * 16 + lc) * L_ + kv + quad * 8);
    oacc = MFMA(pa, vb, oacc);
  }
#pragma unroll
  for (int r = 0; r < 4; ++r)
    O[(size_t)(b * L_ + q0 + quad * 4 + r) * D_ + h * DK_ + w * 16 + lc] =
        f2us(oacc[r]);
}

extern "C" void kernel_launch(void* const* d_in, const int* in_sizes, int n_in,
                              void* d_out, int out_size, void* d_ws, size_t ws_size,
                              hipStream_t stream) {
  const float* query   = (const float*)d_in[0];
  const float* key     = (const float*)d_in[1];
  const float* value   = (const float*)d_in[2];
  const float* wq_w    = (const float*)d_in[3];
  const float* wq_b    = (const float*)d_in[4];
  const float* wk_w    = (const float*)d_in[5];
  const float* wk_b    = (const float*)d_in[6];
  const float* wv_w    = (const float*)d_in[7];
  const float* wv_b    = (const float*)d_in[8];
  const float* dense_w = (const float*)d_in[9];
  const float* dense_b = (const float*)d_in[10];
  const float* gate_w  = (const float*)d_in[11];
  const float* gate_b  = (const float*)d_in[12];
  const float* mp_wq_w = (const float*)d_in[13];
  const float* mp_wq_b = (const float*)d_in[14];
  const float* mp_wk_w = (const float*)d_in[15];
  const float* mp_wk_b = (const float*)d_in[16];

  const size_t RSZ = (size_t)BL_ * D_;   // 2,097,152 elems
  const size_t WSZ = (size_t)D_ * D_;    // 262,144 elems
  us16* R0 = (us16*)d_ws;                // 4 MB
  us16* R1 = R0 + RSZ;                   // 4 MB

  float* out0 = (float*)d_out;                 // final out f32 (8 MB)
  float* outm = out0 + (size_t)B_ * L_ * D_;   // m f32 (16 MB)
  us16*  Vt   = (us16*)d_out;                  // V^T bf16 in out bytes [0,4M)

  dim3 blk(256);

  if (ws_size >= ((size_t)20 << 20)) {
    // ws: R0(4M) R1(4M) Wt x6 (3M) Wk (8M) gbuf(16K) = 19.02 MB
    us16* Wt0 = R1 + RSZ;
    us16* mpq_t = Wt0;
    us16* mpk_t = Wt0 + WSZ;
    us16* wq_t  = Wt0 + 2 * WSZ;
    us16* wk_t  = Wt0 + 3 * WSZ;
    us16* wv_t  = Wt0 + 4 * WSZ;
    us16* dw_t  = Wt0 + 5 * WSZ;
    us16* Wk    = Wt0 + 6 * WSZ;                     // 8 MB
    float* gbuf = (float*)(Wk + (size_t)B_ * L_ * L_);  // 16 KB
    us16* qb = (us16*)((char*)d_out + (4u << 20));   // bf16 query, dead before dense

    WT6 wt;
    wt.src[0] = mp_wq_w; wt.dst[0] = mpq_t;
    wt.src[1] = mp_wk_w; wt.dst[1] = mpk_t;
    wt.src[2] = wq_w;    wt.dst[2] = wq_t;
    wt.src[3] = wk_w;    wt.dst[3] = wk_t;
    wt.src[4] = wv_w;    wt.dst[4] = wv_t;
    wt.src[5] = dense_w; wt.dst[5] = dw_t;
    hipLaunchKernelGGL(prep, dim3(896), blk, 0, stream, wt, query, gate_w, gate_b, gbuf, qb);

    GJobs mp;
    mp.j[0] = { nullptr, qb, mpq_t, mp_wq_b, R0, 0, 1 };
    mp.j[1] = { key, nullptr, mpk_t, mp_wk_b, R1, 0, 0 };
    mp.j[2] = mp.j[1];
    hipLaunchKernelGGL(gemm3, dim3(8, 64, 2), blk, 0, stream, mp);
    hipLaunchKernelGGL(mask16<true>, dim3(16, 16, B_), blk, 0, stream,
                       R0, R1, outm, gbuf, Wk);

    GJobs qkv;
    qkv.j[0] = { nullptr, qb, wq_t, wq_b, R0, 0, 1 };
    qkv.j[1] = { key, nullptr, wk_t, wk_b, R1, 0, 0 };
    qkv.j[2] = { value, nullptr, wv_t, wv_b, Vt, 1, 0 };
    hipLaunchKernelGGL(gemm3, dim3(8, 64, 3), blk, 0, stream, qkv);

    hipLaunchKernelGGL(attn8, dim3(L_ / 16, H_, B_), blk, 0, stream, R0, R1, Vt, Wk, R0);
    hipLaunchKernelGGL(gemm_dense, dim3(8, 64), blk, 0, stream, R0, dw_t, dense_b, out0);
  } else {
    // -------- fallback (8 MB ws): round-8 structure --------
    float* gbuf = (float*)((char*)d_out + (4u << 20));
    dim3 gproj(8, 64);
    hipLaunchKernelGGL((gemm16<0, float>), gproj, blk, 0, stream, query, mp_wq_w, mp_wq_b, (void*)R0);
    hipLaunchKernelGGL((gemm16<0, float>), gproj, blk, 0, stream, key,   mp_wk_w, mp_wk_b, (void*)R1);
    hipLaunchKernelGGL(mask16<false>, dim3(16, 16, B_), blk, 0, stream,
                       R0, R1, outm, (const float*)nullptr, (us16*)nullptr);
    hipLaunchKernelGGL((gemm16<0, float>), gproj, blk, 0, stream, query, wq_w, wq_b, (void*)R0);
    hipLaunchKernelGGL((gemm16<0, float>), gproj, blk, 0, stream, key,   wk_w, wk_b, (void*)R1);
    hipLaunchKernelGGL((gemm16<1, float>), gproj, blk, 0, stream, value, wv_w, wv_b, (void*)Vt);
    hipLaunchKernelGGL(gate_kernel, dim3(BL_ / 4), blk, 0, stream, query, gate_w, gate_b, gbuf);
    hipLaunchKernelGGL(attn2_fb, dim3(L_ / 16, H_, B_), blk, 0, stream, R0, R1, Vt, outm, gbuf, R0);
    hipLaunchKernelGGL((gemm16<2, us16>), gproj, blk, 0, stream, R0, dense_w, dense_b, (void*)out0);
  }
}

// Round 16
// 206.385 us; speedup vs baseline: 1.0483x; 1.0013x over previous
//
#include <hip/hip_runtime.h>

#define B_  4
#define L_  1024
#define D_  512
#define H_  8
#define DK_ 64
#define BL_ (B_*L_)

typedef unsigned short us16;   // raw bf16 bits
typedef __attribute__((ext_vector_type(8))) short bf16x8;
typedef __attribute__((ext_vector_type(4))) float f32x4;

__device__ __forceinline__ float us2f(us16 u) {
  union { unsigned int i; float f; } x;
  x.i = ((unsigned int)u) << 16;
  return x.f;
}
__device__ __forceinline__ us16 f2us(float f) {
  union { float f; unsigned int i; } x;
  x.f = f;
  unsigned int r = x.i + 0x7FFFu + ((x.i >> 16) & 1u);  // RNE
  return (us16)(r >> 16);
}
__device__ __forceinline__ us16 cvt_us(float f) { return f2us(f); }
__device__ __forceinline__ us16 cvt_us(us16 u) { return u; }
// hardware base-2 exp (v_exp_f32); args here are bounded (|x| < ~8)
__device__ __forceinline__ float fexp2(float x) {
  return __builtin_amdgcn_exp2f(x);
}

#define MFMA(a, b, c) __builtin_amdgcn_mfma_f32_16x16x32_bf16(a, b, c, 0, 0, 0)

typedef const __attribute__((address_space(1))) unsigned int* gas_u32;
typedef __attribute__((address_space(3))) unsigned int* las_u32;

// ---- async tile staging helpers (attn8-validated pattern) ------------------
__device__ __forceinline__ void stg8(const us16* rowbase, us16* dst, int lane) {
  const us16* src = rowbase + (size_t)(lane >> 3) * 512 +
                    (((lane & 7) ^ (lane >> 3)) * 8);
  __builtin_amdgcn_global_load_lds((gas_u32)src, (las_u32)dst, 16, 0, 0);
}
__device__ __forceinline__ bf16x8 rdz(const us16* buf, int row, int blk) {
  return *(const bf16x8*)&buf[row * 64 + ((blk ^ (row & 7)) * 8)];
}

// ---------------------------------------------------------------------------
// prep v2: fused (a) 6x weight transpose+cvt f32[k][n]->bf16[n][k] [0..383]
//                (b) query f32 -> bf16 (qb) PLUS gate             [384..895]
// ---------------------------------------------------------------------------
struct WT6 {
  const float* src[6];
  us16* dst[6];
};
__global__ __launch_bounds__(256) void prep(WT6 p, const float* __restrict__ query,
    const float* __restrict__ gw, const float* __restrict__ gb,
    float* __restrict__ g, us16* __restrict__ qb) {
  __shared__ us16 T[64][72];
  int id = blockIdx.x;
  const int t = threadIdx.x;
  if (id >= 384) {
    const int cb = id - 384;
    size_t base = (size_t)cb * 4096 + t * 16;
    const float* src = query + base;
    float v[16];
#pragma unroll
    for (int j = 0; j < 16; ++j) v[j] = src[j];
    union { bf16x8 x; us16 u[8]; } a0, a1;
#pragma unroll
    for (int j = 0; j < 8; ++j) { a0.u[j] = f2us(v[j]); a1.u[j] = f2us(v[8 + j]); }
    *(bf16x8*)&qb[base] = a0.x;
    *(bf16x8*)&qb[base + 8] = a1.x;
    const int li = t & 31;
    float pz = 0.f;
#pragma unroll
    for (int j = 0; j < 16; ++j) pz += v[j] * gw[li * 16 + j];
#pragma unroll
    for (int off = 16; off; off >>= 1) pz += __shfl_xor(pz, off);
    if (li == 0) g[cb * 8 + (t >> 5)] = 1.f / (1.f + __expf(-(pz + gb[0])));
    return;
  }
  const int z = id >> 6;
  const int k0 = ((id >> 3) & 7) * 64, n0 = (id & 7) * 64;
  const float* __restrict__ W = p.src[z];
  us16* __restrict__ Wt = p.dst[z];
  {
    int r = t >> 2, c = (t & 3) * 16;
    const float* src = W + (size_t)(k0 + r) * 512 + n0 + c;
    union { bf16x8 v; us16 u[8]; } p0, p1;
#pragma unroll
    for (int j = 0; j < 8; ++j) { p0.u[j] = f2us(src[j]); p1.u[j] = f2us(src[8 + j]); }
    *(bf16x8*)&T[r][c] = p0.v;
    *(bf16x8*)&T[r][c + 8] = p1.v;
  }
  __syncthreads();
  {
    int n = t >> 2, c = (t & 3) * 16;
    union { bf16x8 v; us16 u[8]; } p0, p1;
#pragma unroll
    for (int j = 0; j < 8; ++j) { p0.u[j] = T[c + j][n]; p1.u[j] = T[c + 8 + j][n]; }
    us16* dst = Wt + (size_t)(n0 + n) * 512 + k0 + c;
    *(bf16x8*)dst = p0.v;
    *(bf16x8*)(dst + 8) = p1.v;
  }
}

// gate standalone (fallback path only)
__global__ __launch_bounds__(256) void gate_kernel(
    const float* __restrict__ query, const float* __restrict__ gw,
    const float* __restrict__ gb, float* __restrict__ g) {
  int row = blockIdx.x * 4 + (threadIdx.x >> 6);
  int lane = threadIdx.x & 63;
  float p = 0.f;
  for (int d = lane; d < D_; d += 64) p += query[(size_t)row * D_ + d] * gw[d];
#pragma unroll
  for (int off = 32; off; off >>= 1) p += __shfl_down(p, off);
  if (lane == 0) g[row] = 1.f / (1.f + __expf(-(p + gb[0])));
}

// ---------------------------------------------------------------------------
// Batched projection GEMM, async-staged (validated round 10): 64x64 tile,
// BK=64.  atype 1: A bf16; atype 0: A f32 reg-prefetch + cvt + ds_write.
// mode 1 (Vt) transposes the output tile through LDS -> coalesced writes.
// grid (8, 64, nz).
// ---------------------------------------------------------------------------
struct GJob {
  const float* A; const us16* Ab; const us16* Wt;
  const float* bias; us16* C; int mode; int atype;
};
struct GJobs { GJob j[3]; };

__global__ __launch_bounds__(256) void gemm3(GJobs jobs) {
  __shared__ us16 Abuf[2][64 * 64];
  __shared__ us16 Bbuf[2][64 * 64];
  int f = blockIdx.x + 8 * (blockIdx.y + 64 * blockIdx.z);
  const int cpx = 64 * (int)gridDim.z;           // nwg/8
  f = (f & 7) * cpx + (f >> 3);
  const int bx = f & 7, by = (f >> 3) & 63, bz = f >> 9;
  const GJob J = jobs.j[bz];
  const int tid = threadIdx.x;
  const int w = tid >> 6, lane = tid & 63;
  const int quad = lane >> 4, lc = lane & 15;
  const int row0 = by * 64, col0 = bx * 64;
  f32x4 acc[4] = {};

  const us16* Bg = J.Wt + (size_t)(col0 + w * 16) * 512;
  auto stgB = [&](int k, int cur) {
    stg8(Bg + k * 64, &Bbuf[cur][(w * 16) * 64], lane);
    stg8(Bg + 8 * 512 + k * 64, &Bbuf[cur][(w * 16 + 8) * 64], lane);
  };

  if (J.atype) {
    const us16* Ag = J.Ab + (size_t)(row0 + w * 16) * 512;
    auto stgA = [&](int k, int cur) {
      stg8(Ag + k * 64, &Abuf[cur][(w * 16) * 64], lane);
      stg8(Ag + 8 * 512 + k * 64, &Abuf[cur][(w * 16 + 8) * 64], lane);
    };
    stgA(0, 0); stgB(0, 0);
    stgA(1, 1); stgB(1, 1);
#pragma unroll
    for (int k = 0; k < 8; ++k) {
      const int cur = k & 1;
      if (k < 7) asm volatile("s_waitcnt vmcnt(4)" ::: "memory");
      else       asm volatile("s_waitcnt vmcnt(0)" ::: "memory");
      __builtin_amdgcn_sched_barrier(0);
      __builtin_amdgcn_s_barrier();
      __builtin_amdgcn_sched_barrier(0);
      bf16x8 a0 = rdz(Abuf[cur], w * 16 + lc, quad);
      bf16x8 a1 = rdz(Abuf[cur], w * 16 + lc, 4 + quad);
#pragma unroll
      for (int ct = 0; ct < 4; ++ct) {
        bf16x8 b0 = rdz(Bbuf[cur], ct * 16 + lc, quad);
        bf16x8 b1 = rdz(Bbuf[cur], ct * 16 + lc, 4 + quad);
        acc[ct] = MFMA(a0, b0, acc[ct]);
        acc[ct] = MFMA(a1, b1, acc[ct]);
      }
      __builtin_amdgcn_sched_barrier(0);
      __builtin_amdgcn_s_barrier();
      __builtin_amdgcn_sched_barrier(0);
      if (k + 2 < 8) { stgA(k + 2, cur); stgB(k + 2, cur); }
    }
  } else {
    const int fr = tid >> 2, j0 = (tid & 3) * 2;
    const float* arow = J.A + (size_t)(row0 + fr) * 512 + j0 * 8;
    f32x4 vA[4], vB[4];
    auto ldA = [&](int k, f32x4* v) {
      const float* p = arow + k * 64;
      v[0] = *(const f32x4*)(p);
      v[1] = *(const f32x4*)(p + 4);
      v[2] = *(const f32x4*)(p + 8);
      v[3] = *(const f32x4*)(p + 12);
    };
    auto wrA = [&](us16* abuf, const f32x4* v) {
      union { bf16x8 x; us16 u[8]; } p0, p1;
#pragma unroll
      for (int j = 0; j < 4; ++j) {
        p0.u[j] = f2us(v[0][j]); p0.u[4 + j] = f2us(v[1][j]);
        p1.u[j] = f2us(v[2][j]); p1.u[4 + j] = f2us(v[3][j]);
      }
      us16* wp = abuf + fr * 64;
      *(bf16x8*)&wp[(j0 ^ (fr & 7)) * 8] = p0.x;
      *(bf16x8*)&wp[((j0 + 1) ^ (fr & 7)) * 8] = p1.x;
    };
    ldA(0, vA); stgB(0, 0);
    ldA(1, vB); stgB(1, 1);
#pragma unroll
    for (int k = 0; k < 8; ++k) {
      const int cur = k & 1;
      if (k < 7) asm volatile("s_waitcnt vmcnt(6)" ::: "memory");
      else       asm volatile("s_waitcnt vmcnt(0)" ::: "memory");
      __builtin_amdgcn_sched_barrier(0);
      wrA(&Abuf[cur][0], cur ? vB : vA);
      asm volatile("s_waitcnt lgkmcnt(0)" ::: "memory");
      __builtin_amdgcn_sched_barrier(0);
      __builtin_amdgcn_s_barrier();
      __builtin_amdgcn_sched_barrier(0);
      bf16x8 a0 = rdz(Abuf[cur], w * 16 + lc, quad);
      bf16x8 a1 = rdz(Abuf[cur], w * 16 + lc, 4 + quad);
#pragma unroll
      for (int ct = 0; ct < 4; ++ct) {
        bf16x8 b0 = rdz(Bbuf[cur], ct * 16 + lc, quad);
        bf16x8 b1 = rdz(Bbuf[cur], ct * 16 + lc, 4 + quad);
        acc[ct] = MFMA(a0, b0, acc[ct]);
        acc[ct] = MFMA(a1, b1, acc[ct]);
      }
      __builtin_amdgcn_sched_barrier(0);
      __builtin_amdgcn_s_barrier();
      __builtin_amdgcn_sched_barrier(0);
      if (k + 2 < 8) { ldA(k + 2, cur ? vB : vA); stgB(k + 2, cur); }
    }
  }
  if (J.mode == 0) {
    const int orow = row0 + w * 16 + quad * 4;
#pragma unroll
    for (int ct = 0; ct < 4; ++ct) {
      const int col = col0 + ct * 16 + lc;
      const float bv = J.bias[col];
#pragma unroll
      for (int r = 0; r < 4; ++r)
        J.C[(size_t)(orow + r) * 512 + col] = f2us(acc[ct][r] + bv);
    }
  } else {
    // mode 1: transpose tile via LDS (Abuf is dead), coalesced Vt row writes.
    us16* T = &Abuf[0][0];   // used as [64][72]
    const int lr = w * 16 + quad * 4;   // local kv row base
#pragma unroll
    for (int ct = 0; ct < 4; ++ct) {
      const int col = col0 + ct * 16 + lc;
      const float bv = J.bias[col];
#pragma unroll
      for (int r = 0; r < 4; ++r)
        T[(lr + r) * 72 + ct * 16 + lc] = f2us(acc[ct][r] + bv);
    }
    __syncthreads();
    const int bb = row0 >> 10, kv0 = row0 & 1023, hh = col0 >> 6;
    const int n = tid >> 2, cc = (tid & 3) * 16;
    union { bf16x8 v; us16 u[8]; } p0, p1;
#pragma unroll
    for (int j = 0; j < 8; ++j) {
      p0.u[j] = T[(cc + j) * 72 + n];
      p1.u[j] = T[(cc + 8 + j) * 72 + n];
    }
    us16* dst = J.C + (((size_t)bb * H_ + hh) * DK_ + n) * L_ + kv0 + cc;
    *(bf16x8*)dst = p0.v;
    *(bf16x8*)(dst + 8) = p1.v;
  }
}

// ---------------------------------------------------------------------------
// Dense: C(f32) = A(bf16 ws) @ Wt(bf16 [n][k]) + bias.  Async-staged.
// 64x64, BK=64, XCD swizzle.  grid (8, 64).
// ---------------------------------------------------------------------------
__global__ __launch_bounds__(256) void gemm_dense(
    const us16* __restrict__ A, const us16* __restrict__ Wt,
    const float* __restrict__ bias, float* __restrict__ C) {
  __shared__ us16 Abuf[2][64 * 64];
  __shared__ us16 Bbuf[2][64 * 64];
  int f = blockIdx.x + 8 * blockIdx.y;            // nwg = 512
  f = (f & 7) * 64 + (f >> 3);
  const int bx = f & 7, by = f >> 3;
  const int tid = threadIdx.x;
  const int w = tid >> 6, lane = tid & 63;
  const int quad = lane >> 4, lc = lane & 15;
  const int row0 = by * 64, col0 = bx * 64;
  f32x4 acc[4] = {};
  const us16* Ag = A + (size_t)(row0 + w * 16) * 512;
  const us16* Bg = Wt + (size_t)(col0 + w * 16) * 512;
  auto stg = [&](int k, int cur) {
    stg8(Ag + k * 64, &Abuf[cur][(w * 16) * 64], lane);
    stg8(Ag + 8 * 512 + k * 64, &Abuf[cur][(w * 16 + 8) * 64], lane);
    stg8(Bg + k * 64, &Bbuf[cur][(w * 16) * 64], lane);
    stg8(Bg + 8 * 512 + k * 64, &Bbuf[cur][(w * 16 + 8) * 64], lane);
  };
  stg(0, 0); stg(1, 1);
#pragma unroll
  for (int k = 0; k < 8; ++k) {
    const int cur = k & 1;
    if (k < 7) asm volatile("s_waitcnt vmcnt(4)" ::: "memory");
    else       asm volatile("s_waitcnt vmcnt(0)" ::: "memory");
    __builtin_amdgcn_sched_barrier(0);
    __builtin_amdgcn_s_barrier();
    __builtin_amdgcn_sched_barrier(0);
    bf16x8 a0 = rdz(Abuf[cur], w * 16 + lc, quad);
    bf16x8 a1 = rdz(Abuf[cur], w * 16 + lc, 4 + quad);
#pragma unroll
    for (int ct = 0; ct < 4; ++ct) {
      bf16x8 b0 = rdz(Bbuf[cur], ct * 16 + lc, quad);
      bf16x8 b1 = rdz(Bbuf[cur], ct * 16 + lc, 4 + quad);
      acc[ct] = MFMA(a0, b0, acc[ct]);
      acc[ct] = MFMA(a1, b1, acc[ct]);
    }
    __builtin_amdgcn_sched_barrier(0);
    __builtin_amdgcn_s_barrier();
    __builtin_amdgcn_sched_barrier(0);
    if (k + 2 < 8) stg(k + 2, cur);
  }
  const int orow = row0 + w * 16 + quad * 4;
#pragma unroll
  for (int ct = 0; ct < 4; ++ct) {
    const int col = col0 + ct * 16 + lc;
    const float bv = bias[col];
#pragma unroll
    for (int r = 0; r < 4; ++r)
      C[(size_t)(orow + r) * 512 + col] = acc[ct][r] + bv;
  }
}

// ---------------------------------------------------------------------------
// Mask: m = sigmoid(QP.KP^T / sqrt(512)) -> f32 out.  WK variant also writes
// wk = g + (1-g)*exp(1-m) bf16.  Async-staged.  64x64 tile, BK=64,
// XCD swizzle.  grid (16, 16, B_).
// ---------------------------------------------------------------------------
template <bool WK>
__global__ __launch_bounds__(256) void mask16(
    const us16* __restrict__ QP, const us16* __restrict__ KP,
    float* __restrict__ Mout, const float* __restrict__ gbuf,
    us16* __restrict__ Wk) {
  __shared__ us16 Abuf[2][64 * 64];
  __shared__ us16 Bbuf[2][64 * 64];
  int f = blockIdx.x + 16 * (blockIdx.y + 16 * blockIdx.z);  // nwg = 1024
  f = (f & 7) * 128 + (f >> 3);
  const int bx = f & 15, by = (f >> 4) & 15, b = f >> 8;
  const int tid = threadIdx.x;
  const int w = tid >> 6, lane = tid & 63;
  const int quad = lane >> 4, lc = lane & 15;
  const int row0 = by * 64, col0 = bx * 64;
  f32x4 acc[4] = {};
  const us16* Ag = QP + (size_t)b * L_ * D_ + (size_t)(row0 + w * 16) * 512;
  const us16* Bg = KP + (size_t)b * L_ * D_ + (size_t)(col0 + w * 16) * 512;
  auto stg = [&](int k, int cur) {
    stg8(Ag + k * 64, &Abuf[cur][(w * 16) * 64], lane);
    stg8(Ag + 8 * 512 + k * 64, &Abuf[cur][(w * 16 + 8) * 64], lane);
    stg8(Bg + k * 64, &Bbuf[cur][(w * 16) * 64], lane);
    stg8(Bg + 8 * 512 + k * 64, &Bbuf[cur][(w * 16 + 8) * 64], lane);
  };
  stg(0, 0); stg(1, 1);
#pragma unroll
  for (int k = 0; k < 8; ++k) {
    const int cur = k & 1;
    if (k < 7) asm volatile("s_waitcnt vmcnt(4)" ::: "memory");
    else       asm volatile("s_waitcnt vmcnt(0)" ::: "memory");
    __builtin_amdgcn_sched_barrier(0);
    __builtin_amdgcn_s_barrier();
    __builtin_amdgcn_sched_barrier(0);
    bf16x8 a0 = rdz(Abuf[cur], w * 16 + lc, quad);
    bf16x8 a1 = rdz(Abuf[cur], w * 16 + lc, 4 + quad);
#pragma unroll
    for (int ct = 0; ct < 4; ++ct) {
      bf16x8 b0 = rdz(Bbuf[cur], ct * 16 + lc, quad);
      bf16x8 b1 = rdz(Bbuf[cur], ct * 16 + lc, 4 + quad);
      acc[ct] = MFMA(a0, b0, acc[ct]);
      acc[ct] = MFMA(a1, b1, acc[ct]);
    }
    __builtin_amdgcn_sched_barrier(0);
    __builtin_amdgcn_s_barrier();
    __builtin_amdgcn_sched_barrier(0);
    if (k + 2 < 8) stg(k + 2, cur);
  }
  const float sc2 = 0.04419417382415922f;  // 1/sqrt(512)
  const int orow = row0 + w * 16 + quad * 4;
  float gq[4];
  if (WK) {
#pragma unroll
    for (int r = 0; r < 4; ++r) gq[r] = gbuf[b * L_ + orow + r];
  }
#pragma unroll
  for (int ct = 0; ct < 4; ++ct) {
    const int col = col0 + ct * 16 + lc;
#pragma unroll
    for (int r = 0; r < 4; ++r) {
      float x = acc[ct][r] * sc2;
      float v = 1.f / (1.f + __expf(-x));
      size_t idx = ((size_t)b * L_ + orow + r) * L_ + col;
      Mout[idx] = v;
      if (WK) Wk[idx] = f2us(gq[r] + (1.f - gq[r]) * __expf(1.f - v));
    }
  }
}

// ---------------------------------------------------------------------------
// Attention v8 (validated best: 51.7us r10; cross-round noise 52-62us):
// attn5 + 4-deep async K staging, counted vmcnt, XOR swizzle.
// ---------------------------------------------------------------------------
__global__ __launch_bounds__(256, 4) void attn8(
    const us16* Qp, const us16* __restrict__ Kp,
    const us16* __restrict__ Vt, const us16* __restrict__ Wk, us16* O) {
  __shared__ us16 P[16 * 1032];   // pass1: [0,32KB) = K staging; pass2: P
  __shared__ float red[2][4][16];
  const int tid = threadIdx.x;
  const int w = tid >> 6, lane = tid & 63;
  const int quad = lane >> 4, lc = lane & 15;
  int raw = blockIdx.x + 64 * (blockIdx.y + 8 * blockIdx.z);
  const int c = raw & 7;
  const int rest = raw >> 3;            // [0,256)
  const int gg = c * 4 + (rest & 3);    // (b,h) combo; same -> same XCD
  const int q0 = (rest >> 2) * 16;
  const int h = gg & 7, b = gg >> 3;

  const us16* qptr = Qp + (size_t)(b * L_ + q0 + lc) * D_ + h * DK_;
  bf16x8 qa0 = *(const bf16x8*)(qptr + quad * 8);
  bf16x8 qa1 = *(const bf16x8*)(qptr + 32 + quad * 8);

  const us16* Kbase = Kp + (size_t)b * L_ * D_ + h * DK_;
  const int srow = lane >> 3;
  const int sblk = ((lane & 7) ^ srow) * 8;
  us16* kst = &P[w * 4096];

  auto stage = [&](int kt, int d) {
#pragma unroll
    for (int i = 0; i < 2; ++i) {
      const us16* src =
          Kbase + (size_t)(kt * 64 + w * 16 + i * 8 + srow) * D_ + sblk;
      __builtin_amdgcn_global_load_lds(
          (gas_u32)src, (las_u32)(kst + d * 1024 + i * 512), 16, 0, 0);
    }
  };

  const float c1 = 0.18033688011112042f;  // 0.125 * log2(e)

  stage(0, 0); stage(1, 1); stage(2, 2); stage(3, 3);

  float s[16][4];
  float sm[4] = {0.f, 0.f, 0.f, 0.f};
#pragma unroll
  for (int kt = 0; kt < 16; ++kt) {
    const int d = kt & 3;
    if (kt <= 12)      asm volatile("s_waitcnt vmcnt(6)" ::: "memory");
    else if (kt == 13) asm volatile("s_waitcnt vmcnt(4)" ::: "memory");
    else if (kt == 14) asm volatile("s_waitcnt vmcnt(2)" ::: "memory");
    else               asm volatile("s_waitcnt vmcnt(0)" ::: "memory");
    __builtin_amdgcn_sched_barrier(0);
    bf16x8 b0 = *(const bf16x8*)&kst[d * 1024 + lc * 64 + ((quad ^ (lc & 7)) * 8)];
    bf16x8 b1 = *(const bf16x8*)&kst[d * 1024 + lc * 64 + (((4 + quad) ^ (lc & 7)) * 8)];
    if (kt + 4 < 16) stage(kt + 4, d);
    f32x4 a = {};
    __builtin_amdgcn_s_setprio(1);
    a = MFMA(qa0, b0, a);
    a = MFMA(qa1, b1, a);
    __builtin_amdgcn_s_setprio(0);
#pragma unroll
    for (int r = 0; r < 4; ++r) {
      float e = fexp2(a[r] * c1);
      s[kt][r] = e;
      sm[r] += e;
    }
    __builtin_amdgcn_sched_barrier(0);
  }
#pragma unroll
  for (int r = 0; r < 4; ++r)
#pragma unroll
    for (int off = 1; off < 16; off <<= 1) sm[r] += __shfl_xor(sm[r], off);
  if (lc == 0)
#pragma unroll
    for (int r = 0; r < 4; ++r) red[0][w][quad * 4 + r] = sm[r];
  __syncthreads();
  float invr[4];  // log2(e) / sum1 (folds the 2nd-exp base conversion)
#pragma unroll
  for (int r = 0; r < 4; ++r) {
    const int row = quad * 4 + r;
    invr[r] = 1.44269504088896341f /
              (red[0][0][row] + red[0][1][row] + red[0][2][row] + red[0][3][row]);
  }

  const us16* wkb = Wk + (size_t)(b * L_ + q0 + quad * 4) * L_ + w * 16 + lc;
  float ts[4] = {0.f, 0.f, 0.f, 0.f};
#pragma unroll
  for (int kt = 0; kt < 16; ++kt) {
#pragma unroll
    for (int r = 0; r < 4; ++r) {
      float cv = s[kt][r] * invr[r] * us2f(wkb[(size_t)r * L_ + kt * 64]);
      float e2 = fexp2(cv);
      ts[r] += e2;
      P[(quad * 4 + r) * 1032 + kt * 64 + w * 16 + lc] = f2us(e2);
    }
  }
#pragma unroll
  for (int r = 0; r < 4; ++r)
#pragma unroll
    for (int off = 1; off < 16; off <<= 1) ts[r] += __shfl_xor(ts[r], off);
  if (lc == 0)
#pragma unroll
    for (int r = 0; r < 4; ++r) red[1][w][quad * 4 + r] = ts[r];
  __syncthreads();  // single barrier covers P writes AND red[1]

  const us16* Vb = Vt + ((size_t)(b * H_ + h) * DK_ + w * 16 + lc) * L_;
  f32x4 oacc = {};
  for (int kv = 0; kv < L_; kv += 32) {
    bf16x8 pa = *(const bf16x8*)&P[lc * 1032 + kv + quad * 8];
    bf16x8 vb = *(const bf16x8*)(Vb + kv + quad * 8);
    __builtin_amdgcn_s_setprio(1);
    oacc = MFMA(pa, vb, oacc);
    __builtin_amdgcn_s_setprio(0);
  }
#pragma unroll
  for (int r = 0; r < 4; ++r) {
    const int row = quad * 4 + r;
    float inv2 = 1.f /
        (red[1][0][row] + red[1][1][row] + red[1][2][row] + red[1][3][row]);
    O[(size_t)(b * L_ + q0 + row) * D_ + h * DK_ + w * 16 + lc] =
        f2us(oacc[r] * inv2);
  }
}

// ---------------------------------------------------------------------------
// Fallback kernels (small ws): round-8 path.
// ---------------------------------------------------------------------------
template <int MODE, typename TA>
__global__ __launch_bounds__(256) void gemm16(
    const TA* __restrict__ A, const float* __restrict__ W,
    const float* __restrict__ bias, void* __restrict__ Cout) {
  __shared__ us16 Al[64][56];
  __shared__ us16 Wl[64][56];
  const int tid = threadIdx.x;
  const int w = tid >> 6, lane = tid & 63;
  const int quad = lane >> 4, lc = lane & 15;
  const int row0 = blockIdx.y * 64, col0 = blockIdx.x * 64;
  f32x4 acc[4] = {};
  const int arow = tid >> 2, aks = (tid & 3) * 8;
  const int wk = tid & 31, wns = (tid >> 5) * 8;
  for (int k0 = 0; k0 < 512; k0 += 32) {
    {
      union { bf16x8 v; us16 u[8]; } pk;
      const TA* src = A + (size_t)(row0 + arow) * 512 + k0 + aks;
#pragma unroll
      for (int j = 0; j < 8; ++j) pk.u[j] = cvt_us(src[j]);
      *(bf16x8*)&Al[arow][aks] = pk.v;
    }
    {
      const float* src = W + (size_t)(k0 + wk) * 512 + col0 + wns;
#pragma unroll
      for (int j = 0; j < 8; ++j) Wl[wns + j][wk] = f2us(src[j]);
    }
    __syncthreads();
    bf16x8 af = *(const bf16x8*)&Al[w * 16 + lc][quad * 8];
#pragma unroll
    for (int ct = 0; ct < 4; ++ct) {
      bf16x8 bf = *(const bf16x8*)&Wl[ct * 16 + lc][quad * 8];
      acc[ct] = MFMA(af, bf, acc[ct]);
    }
    __syncthreads();
  }
  const int orow = row0 + w * 16 + quad * 4;
#pragma unroll
  for (int ct = 0; ct < 4; ++ct) {
    const int col = col0 + ct * 16 + lc;
    const float bv = bias[col];
    if (MODE == 0) {
      us16* C = (us16*)Cout;
#pragma unroll
      for (int r = 0; r < 4; ++r)
        C[(size_t)(orow + r) * 512 + col] = f2us(acc[ct][r] + bv);
    } else if (MODE == 1) {
      us16* C = (us16*)Cout;
      const int h = col >> 6, dk = col & 63;
#pragma unroll
      for (int r = 0; r < 4; ++r) {
        const int grow = orow + r;
        const int b = grow >> 10, kv = grow & 1023;
        C[(((size_t)b * H_ + h) * DK_ + dk) * L_ + kv] = f2us(acc[ct][r] + bv);
      }
    } else {
      float* C = (float*)Cout;
#pragma unroll
      for (int r = 0; r < 4; ++r)
        C[(size_t)(orow + r) * 512 + col] = acc[ct][r] + bv;
    }
  }
}

__global__ __launch_bounds__(256, 3) void attn2_fb(
    const us16* Qp, const us16* __restrict__ Kp,
    const us16* __restrict__ Vt, const float* __restrict__ Mm,
    const float* __restrict__ gbuf, us16* O) {
  __shared__ us16 Ql[16][72];
  __shared__ us16 P[16 * 1032];
  __shared__ float red[2][4][16];
  const int tid = threadIdx.x;
  const int w = tid >> 6, lane = tid & 63;
  const int quad = lane >> 4, lc = lane & 15;
  const int b = blockIdx.z, h = blockIdx.y, q0 = blockIdx.x * 16;
  if (tid < 128) {
    int r = tid >> 3, ks = (tid & 7) * 8;
    *(bf16x8*)&Ql[r][ks] =
        *(const bf16x8*)(Qp + (size_t)(b * L_ + q0 + r) * D_ + h * DK_ + ks);
  }
  __syncthreads();
  bf16x8 qa0 = *(const bf16x8*)&Ql[lc][quad * 8];
  bf16x8 qa1 = *(const bf16x8*)&Ql[lc][32 + quad * 8];
  const us16* Kbase = Kp + (size_t)b * L_ * D_ + h * DK_;
  float s[16][4];
#pragma unroll
  for (int kt = 0; kt < 16; ++kt) {
    const us16* kr = Kbase + (size_t)(kt * 64 + w * 16 + lc) * D_;
    bf16x8 b0 = *(const bf16x8*)(kr + quad * 8);
    bf16x8 b1 = *(const bf16x8*)(kr + 32 + quad * 8);
    f32x4 a = {};
    a = MFMA(qa0, b0, a);
    a = MFMA(qa1, b1, a);
#pragma unroll
    for (int r = 0; r < 4; ++r) s[kt][r] = a[r] * 0.125f;
  }
  float sm[4];
#pragma unroll
  for (int r = 0; r < 4; ++r) {
    float t = 0.f;
#pragma unroll
    for (int kt = 0; kt < 16; ++kt) { s[kt][r] = __expf(s[kt][r]); t += s[kt][r]; }
#pragma unroll
    for (int off = 1; off < 16; off <<= 1) t += __shfl_xor(t, off);
    sm[r] = t;
  }
  if (lc == 0)
#pragma unroll
    for (int r = 0; r < 4; ++r) red[0][w][quad * 4 + r] = sm[r];
  __syncthreads();
  float inv[4];
#pragma unroll
  for (int r = 0; r < 4; ++r) {
    const int row = quad * 4 + r;
    inv[r] = 1.f / (red[0][0][row] + red[0][1][row] + red[0][2][row] + red[0][3][row]);
  }
  float gq[4];
#pragma unroll
  for (int r = 0; r < 4; ++r) gq[r] = gbuf[b * L_ + q0 + quad * 4 + r];
#pragma unroll
  for (int r = 0; r < 4; ++r) {
    const float* mrow = Mm + (size_t)(b * L_ + q0 + quad * 4 + r) * L_;
    float t = 0.f;
#pragma unroll
    for (int kt = 0; kt < 16; ++kt) {
      float mval = mrow[kt * 64 + w * 16 + lc];
      float c = s[kt][r] * inv[r] * (gq[r] + (1.f - gq[r]) * __expf(1.f - mval));
      float e = __expf(c);
      s[kt][r] = e;
      t += e;
    }
#pragma unroll
    for (int off = 1; off < 16; off <<= 1) t += __shfl_xor(t, off);
    sm[r] = t;
  }
  if (lc == 0)
#pragma unroll
    for (int r = 0; r < 4; ++r) red[1][w][quad * 4 + r] = sm[r];
  __syncthreads();
#pragma unroll
  for (int r = 0; r < 4; ++r) {
    const int row = quad * 4 + r;
    inv[r] = 1.f / (red[1][0][row] + red[1][1][row] + red[1][2][row] + red[1][3][row]);
  }
#pragma unroll
  for (int kt = 0; kt < 16; ++kt)
#pragma unroll
    for (int r = 0; r < 4; ++r)
      P[(quad * 4 + r) * 1032 + kt * 64 + w * 16 + lc] = f2us(s[kt][r] * inv[r]);
  __syncthreads();
  const us16* Vb = Vt + (size_t)(b * H_ + h) * DK_ * L_;
  f32x4 oacc = {};
  for (int kv = 0; kv < L_; kv += 32) {
    bf16x8 pa = *(const bf16x8*)&P[lc * 1032 + kv + quad * 8];
    bf16x8 vb = *(const bf16x8*)(Vb + (size_t)(w * 16 + lc) * L_ + kv + quad * 8);
    oacc = MFMA(pa, vb, oacc);
  }
#pragma unroll
  for (int r = 0; r < 4; ++r)
    O[(size_t)(b * L_ + q0 + quad * 4 + r) * D_ + h * DK_ + w * 16 + lc] =
        f2us(oacc[r]);
}

extern "C" void kernel_launch(void* const* d_in, const int* in_sizes, int n_in,
                              void* d_out, int out_size, void* d_ws, size_t ws_size,
                              hipStream_t stream) {
  const float* query   = (const float*)d_in[0];
  const float* key     = (const float*)d_in[1];
  const float* value   = (const float*)d_in[2];
  const float* wq_w    = (const float*)d_in[3];
  const float* wq_b    = (const float*)d_in[4];
  const float* wk_w    = (const float*)d_in[5];
  const float* wk_b    = (const float*)d_in[6];
  const float* wv_w    = (const float*)d_in[7];
  const float* wv_b    = (const float*)d_in[8];
  const float* dense_w = (const float*)d_in[9];
  const float* dense_b = (const float*)d_in[10];
  const float* gate_w  = (const float*)d_in[11];
  const float* gate_b  = (const float*)d_in[12];
  const float* mp_wq_w = (const float*)d_in[13];
  const float* mp_wq_b = (const float*)d_in[14];
  const float* mp_wk_w = (const float*)d_in[15];
  const float* mp_wk_b = (const float*)d_in[16];

  const size_t RSZ = (size_t)BL_ * D_;   // 2,097,152 elems
  const size_t WSZ = (size_t)D_ * D_;    // 262,144 elems
  us16* R0 = (us16*)d_ws;                // 4 MB
  us16* R1 = R0 + RSZ;                   // 4 MB

  float* out0 = (float*)d_out;                 // final out f32 (8 MB)
  float* outm = out0 + (size_t)B_ * L_ * D_;   // m f32 (16 MB)
  us16*  Vt   = (us16*)d_out;                  // V^T bf16 in out bytes [0,4M)

  dim3 blk(256);

  if (ws_size >= ((size_t)20 << 20)) {
    // ws: R0(4M) R1(4M) Wt x6 (3M) Wk (8M) gbuf(16K) = 19.02 MB
    us16* Wt0 = R1 + RSZ;
    us16* mpq_t = Wt0;
    us16* mpk_t = Wt0 + WSZ;
    us16* wq_t  = Wt0 + 2 * WSZ;
    us16* wk_t  = Wt0 + 3 * WSZ;
    us16* wv_t  = Wt0 + 4 * WSZ;
    us16* dw_t  = Wt0 + 5 * WSZ;
    us16* Wk    = Wt0 + 6 * WSZ;                     // 8 MB
    float* gbuf = (float*)(Wk + (size_t)B_ * L_ * L_);  // 16 KB
    us16* qb = (us16*)((char*)d_out + (4u << 20));   // bf16 query, dead before dense

    WT6 wt;
    wt.src[0] = mp_wq_w; wt.dst[0] = mpq_t;
    wt.src[1] = mp_wk_w; wt.dst[1] = mpk_t;
    wt.src[2] = wq_w;    wt.dst[2] = wq_t;
    wt.src[3] = wk_w;    wt.dst[3] = wk_t;
    wt.src[4] = wv_w;    wt.dst[4] = wv_t;
    wt.src[5] = dense_w; wt.dst[5] = dw_t;
    hipLaunchKernelGGL(prep, dim3(896), blk, 0, stream, wt, query, gate_w, gate_b, gbuf, qb);

    // launch 2: mp projections + V projection (V has no mask16 dependency;
    // moving it here shortens the attn-gating launch below)
    GJobs mpv;
    mpv.j[0] = { nullptr, qb, mpq_t, mp_wq_b, R0, 0, 1 };
    mpv.j[1] = { key, nullptr, mpk_t, mp_wk_b, R1, 0, 0 };
    mpv.j[2] = { value, nullptr, wv_t, wv_b, Vt, 1, 0 };
    hipLaunchKernelGGL(gemm3, dim3(8, 64, 3), blk, 0, stream, mpv);
    hipLaunchKernelGGL(mask16<true>, dim3(16, 16, B_), blk, 0, stream,
                       R0, R1, outm, gbuf, Wk);

    // launch 4: only the Q/K projections attn needs (2 jobs, was 3)
    GJobs qk;
    qk.j[0] = { nullptr, qb, wq_t, wq_b, R0, 0, 1 };
    qk.j[1] = { key, nullptr, wk_t, wk_b, R1, 0, 0 };
    qk.j[2] = qk.j[1];
    hipLaunchKernelGGL(gemm3, dim3(8, 64, 2), blk, 0, stream, qk);

    hipLaunchKernelGGL(attn8, dim3(L_ / 16, H_, B_), blk, 0, stream, R0, R1, Vt, Wk, R0);
    hipLaunchKernelGGL(gemm_dense, dim3(8, 64), blk, 0, stream, R0, dw_t, dense_b, out0);
  } else {
    // -------- fallback (8 MB ws): round-8 structure --------
    float* gbuf = (float*)((char*)d_out + (4u << 20));
    dim3 gproj(8, 64);
    hipLaunchKernelGGL((gemm16<0, float>), gproj, blk, 0, stream, query, mp_wq_w, mp_wq_b, (void*)R0);
    hipLaunchKernelGGL((gemm16<0, float>), gproj, blk, 0, stream, key,   mp_wk_w, mp_wk_b, (void*)R1);
    hipLaunchKernelGGL(mask16<false>, dim3(16, 16, B_), blk, 0, stream,
                       R0, R1, outm, (const float*)nullptr, (us16*)nullptr);
    hipLaunchKernelGGL((gemm16<0, float>), gproj, blk, 0, stream, query, wq_w, wq_b, (void*)R0);
    hipLaunchKernelGGL((gemm16<0, float>), gproj, blk, 0, stream, key,   wk_w, wk_b, (void*)R1);
    hipLaunchKernelGGL((gemm16<1, float>), gproj, blk, 0, stream, value, wv_w, wv_b, (void*)Vt);
    hipLaunchKernelGGL(gate_kernel, dim3(BL_ / 4), blk, 0, stream, query, gate_w, gate_b, gbuf);
    hipLaunchKernelGGL(attn2_fb, dim3(L_ / 16, H_, B_), blk, 0, stream, R0, R1, Vt, outm, gbuf, R0);
    hipLaunchKernelGGL((gemm16<2, us16>), gproj, blk, 0, stream, R0, dense_w, dense_b, (void*)out0);
  }
}